// Round 1
// 438.088 us; speedup vs baseline: 1.0252x; 1.0252x over previous
//
#include <hip/hip_runtime.h>
#include <hip/hip_bf16.h>

typedef __bf16 bf16x8_t __attribute__((ext_vector_type(8)));
typedef float  f32x4_t  __attribute__((ext_vector_type(4)));

#define B_     2
#define L_     2048
#define D_     2048
#define H_     16
#define DH_    128
#define INNER_ 2048
#define M_     (B_ * L_)

// async global->LDS, 16B per lane. LDS dest must be wave-uniform base + lane*16.
__device__ __forceinline__ void gld_lds16(const void* g, void* l) {
    __builtin_amdgcn_global_load_lds(
        (const __attribute__((address_space(1))) void*)g,
        (__attribute__((address_space(3))) void*)l,
        16, 0, 0);
}

__device__ __forceinline__ unsigned short f2bf(float f) {
    __hip_bfloat16 h = __float2bfloat16(f);
    return *(unsigned short*)&h;
}
__device__ __forceinline__ float bf2f(unsigned short s) {
    return __uint_as_float(((unsigned)s) << 16);
}

// ---------------------------------------------------------------- cast f32 -> bf16
__global__ __launch_bounds__(256)
void k_cast(const float* __restrict__ in, unsigned short* __restrict__ out) {
    const size_t i = ((size_t)blockIdx.x * 256 + threadIdx.x) * 4;
    float4 v = *(const float4*)(in + i);
    ushort4 o;
    o.x = f2bf(v.x); o.y = f2bf(v.y); o.z = f2bf(v.z); o.w = f2bf(v.w);
    *(ushort4*)(out + i) = o;
}

// ---------------------------------------------------------------- fused 4x transpose+cast
__global__ __launch_bounds__(256)
void k_wtrans4(const float* __restrict__ w0, const float* __restrict__ w1,
               const float* __restrict__ w2, const float* __restrict__ w3,
               unsigned short* __restrict__ d0, unsigned short* __restrict__ d1,
               unsigned short* __restrict__ d2, unsigned short* __restrict__ d3) {
    const int z = blockIdx.z;
    const float* in = (z == 0) ? w0 : (z == 1) ? w1 : (z == 2) ? w2 : w3;
    unsigned short* out = (z == 0) ? d0 : (z == 1) ? d1 : (z == 2) ? d2 : d3;
    __shared__ unsigned short tile[32][33];
    const int t  = threadIdx.x;
    const int r  = t >> 3;
    const int c4 = (t & 7) << 2;
    const size_t ib = ((size_t)blockIdx.y * 32 + r) * 2048 + blockIdx.x * 32 + c4;
    float4 v = *(const float4*)(in + ib);
    tile[r][c4 + 0] = f2bf(v.x); tile[r][c4 + 1] = f2bf(v.y);
    tile[r][c4 + 2] = f2bf(v.z); tile[r][c4 + 3] = f2bf(v.w);
    __syncthreads();
    ushort4 o;
    o.x = tile[c4 + 0][r]; o.y = tile[c4 + 1][r];
    o.z = tile[c4 + 2][r]; o.w = tile[c4 + 3][r];
    const size_t ob = ((size_t)blockIdx.x * 32 + r) * 2048 + blockIdx.y * 32 + c4;
    *(ushort4*)(out + ob) = o;
}

// ---------------------------------------------------------------- GEMM core macro body (128^2, kept for wo-GEMM)
#define GEMM_BODY(A_, Bt_, K_)                                                 \
    __shared__ __align__(16) __hip_bfloat16 As[128 * 32];                      \
    __shared__ __align__(16) __hip_bfloat16 Bs[128 * 32];                      \
    const int t    = threadIdx.x;                                              \
    const int lane = t & 63;                                                   \
    const int wave = t >> 6;                                                   \
    const int quad = lane >> 4;                                                \
    const int l16  = lane & 15;                                                \
    const int wm   = (wave >> 1) * 64;                                         \
    const int wn   = (wave & 1) * 64;                                          \
    const int srow = t >> 2;                                                   \
    const int scol = (t & 3) << 3;                                             \
    const __hip_bfloat16* Ag = A_  + (size_t)(tileM + srow) * K_ + scol;       \
    const __hip_bfloat16* Bg = Bt_ + (size_t)(tileN + srow) * K_ + scol;       \
    __hip_bfloat16* Asl  = &As[t * 8];                                         \
    __hip_bfloat16* Asl2 = &As[2048 + t * 8];                                  \
    __hip_bfloat16* Bsl  = &Bs[t * 8];                                         \
    __hip_bfloat16* Bsl2 = &Bs[2048 + t * 8];                                  \
    const size_t rowskip = (size_t)64 * K_;                                    \
    f32x4_t acc[4][4];                                                         \
    _Pragma("unroll") for (int i = 0; i < 4; i++)                              \
        _Pragma("unroll") for (int j = 0; j < 4; j++)                          \
            acc[i][j] = (f32x4_t){0.f, 0.f, 0.f, 0.f};                         \
    for (int k0 = 0; k0 < K_; k0 += 32) {                                      \
        __syncthreads();                                                       \
        gld_lds16(Ag + k0,           Asl);                                     \
        gld_lds16(Ag + rowskip + k0, Asl2);                                    \
        gld_lds16(Bg + k0,           Bsl);                                     \
        gld_lds16(Bg + rowskip + k0, Bsl2);                                    \
        __syncthreads();                                                       \
        bf16x8_t af[4], bfr[4];                                                \
        _Pragma("unroll") for (int i = 0; i < 4; i++)                          \
            af[i] = *(const bf16x8_t*)&As[(wm + i * 16 + l16) * 32 + quad * 8];\
        _Pragma("unroll") for (int j = 0; j < 4; j++)                          \
            bfr[j] = *(const bf16x8_t*)&Bs[(wn + j * 16 + l16) * 32 + quad * 8];\
        _Pragma("unroll") for (int i = 0; i < 4; i++)                          \
            _Pragma("unroll") for (int j = 0; j < 4; j++)                      \
                acc[i][j] = __builtin_amdgcn_mfma_f32_16x16x32_bf16(           \
                    af[i], bfr[j], acc[i][j], 0, 0, 0);                        \
    }

// wo GEMM: f32 output to d_out
__global__ __launch_bounds__(256)
void k_gemm_bt_f32(const __hip_bfloat16* __restrict__ A,
                   const __hip_bfloat16* __restrict__ Bt,
                   const float* __restrict__ bias,
                   float* __restrict__ C,
                   int M, int N, int K) {
    const int tileM = blockIdx.x * 128;
    const int tileN = blockIdx.y * 128;
    GEMM_BODY(A, Bt, K)
#pragma unroll
    for (int i = 0; i < 4; i++)
#pragma unroll
        for (int r = 0; r < 4; r++) {
            const int m = tileM + wm + i * 16 + quad * 4 + r;
#pragma unroll
            for (int j = 0; j < 4; j++) {
                const int n = tileN + wn + j * 16 + l16;
                C[(size_t)m * N + n] = acc[i][j][r] + bias[n];
            }
        }
}

// ---------------------------------------------------------------- fused QKV GEMM
// 256x256 tile, BK=64, 8 waves (2Mx4N), 8-phase schedule with counted vmcnt
// (T1 XCD swizzle + T2 LDS XOR swizzle + T3/T4 phased counted-vmcnt + T5 setprio).
//
// LDS per buffer (elems): A_lo[128][64] @0, A_hi[128][64] @8192,
//   B_even (n-stripes 0-31,64-95,128-159,192-223 packed) @16384,
//   B_odd @24576. Two buffers (tile parity), 65536 elems = 128 KiB.
// Chunk swizzle: 8-bf16 chunk q stored at slot q^(row&7); staged via
// pre-swizzled GLOBAL source + linear LDS dest (rule 21), read with same XOR.
//
// Phase (mi,ni) computes acc[mi*4+i][ni*2+jj], both k-chunks (16 MFMA).
// Region liveness ledger (iter computes T0=2it in buf0 @P1-4, T1 in buf1 @P5-8):
//   P1 stage buf1.B_odd(T1)+buf1.A_lo(T1)   (old read last iter P6..P8 - dead)
//   P2 stage buf1.A_hi(T1)
//   P4 stage buf0.B_even(T2)  (old read P1,P3 - dead)  + vmcnt(2) [retires T1]
//   P5 stage buf0.B_odd(T2)+buf0.A_lo(T2)   (old read thru P4 - dead)
//   P6 stage buf0.A_hi(T2)
//   P8 stage buf1.B_even(T3)  (old read P5,P7 - dead)  + vmcnt(2) [retires T2]
// Per-wave ticks: 2/unit; at each wait 10 outstanding -> retire 8, leave 2.
#define FENCE asm volatile("" ::: "memory")
#define BAR   do { FENCE; __builtin_amdgcn_s_barrier(); FENCE; } while (0)
#define WLGKM asm volatile("s_waitcnt lgkmcnt(0)" ::: "memory")
#define WVM2  asm volatile("s_waitcnt vmcnt(2)" ::: "memory")
#define WVM0  asm volatile("s_waitcnt vmcnt(0)" ::: "memory")

#define STG_A(bufe, hi, kt) do {                                                        \
    gld_lds16(aS + (size_t)(hi) * (128 * D_) + (kt) * 64,                               \
              &lds[(bufe) + (hi) * 8192 + t * 8]);                                      \
    gld_lds16(aS + (size_t)(hi) * (128 * D_) + (size_t)64 * D_ + (kt) * 64,             \
              &lds[(bufe) + (hi) * 8192 + 4096 + t * 8]);                               \
} while (0)
#define STG_B(bufe, eo, kt) do {                                                        \
    gld_lds16(bS + (rB0 + (eo) * 32) * (size_t)D_ + (kt) * 64,                          \
              &lds[(bufe) + 16384 + (eo) * 8192 + t * 8]);                              \
    gld_lds16(bS + (rB1 + (eo) * 32) * (size_t)D_ + (kt) * 64,                          \
              &lds[(bufe) + 16384 + (eo) * 8192 + 4096 + t * 8]);                       \
} while (0)
#define DSA(bufe, mi) do {                                                              \
    _Pragma("unroll") for (int kk = 0; kk < 2; kk++)                                    \
    _Pragma("unroll") for (int i = 0; i < 4; i++)                                       \
        af[kk][i] = *(const bf16x8_t*)&lds[(bufe) + aroff +                             \
            ((mi) * 64 + i * 16 + l16) * 64 + (kk ? sw1 : sw0)];                        \
} while (0)
#define DSB(bufe, ni) do {                                                              \
    _Pragma("unroll") for (int kk = 0; kk < 2; kk++)                                    \
    _Pragma("unroll") for (int jj = 0; jj < 2; jj++)                                    \
        bfr[kk][jj] = *(const bf16x8_t*)&lds[(bufe) + 16384 + (ni) * 8192 +             \
            ((wave & 3) * 32 + jj * 16 + l16) * 64 + (kk ? sw1 : sw0)];                 \
} while (0)
#define MM(mi, ni) do {                                                                 \
    __builtin_amdgcn_s_setprio(1);                                                      \
    _Pragma("unroll") for (int kk = 0; kk < 2; kk++)                                    \
    _Pragma("unroll") for (int i = 0; i < 4; i++)                                       \
    _Pragma("unroll") for (int jj = 0; jj < 2; jj++)                                    \
        acc[(mi) * 4 + i][(ni) * 2 + jj] = __builtin_amdgcn_mfma_f32_16x16x32_bf16(     \
            af[kk][i], bfr[kk][jj], acc[(mi) * 4 + i][(ni) * 2 + jj], 0, 0, 0);         \
    __builtin_amdgcn_s_setprio(0);                                                      \
} while (0)

__global__ __launch_bounds__(512, 2)
void k_gemm_qkv(const __hip_bfloat16* __restrict__ A,
                const __hip_bfloat16* __restrict__ Bt,
                const float* __restrict__ bq, const float* __restrict__ bk,
                const float* __restrict__ bv,
                __hip_bfloat16* __restrict__ qo, __hip_bfloat16* __restrict__ ko,
                __hip_bfloat16* __restrict__ vTo) {
    __shared__ __align__(16) __hip_bfloat16 lds[65536];  // 128 KiB

    // bijective XCD swizzle (384 % 8 == 0); bx fast-varying -> per-XCD B hot-set ~3MB
    const int nwg = gridDim.x;                  // 384
    const int wg  = blockIdx.x;
    const int sw  = (wg & 7) * (nwg >> 3) + (wg >> 3);
    const int bx  = sw & 15;                    // 16 M-tiles
    const int by  = sw >> 4;                    // 24 N-tiles
    const int tileM = bx << 8;
    const int tileN = by << 8;

    const int t    = threadIdx.x;
    const int lane = t & 63;
    const int wave = t >> 6;
    const int quad = lane >> 4;
    const int l16  = lane & 15;
    const int wm   = (wave >> 2) << 7;          // 0 / 128
    const int wn   = (wave & 3) << 6;           // 0/64/128/192

    // read-side constants
    const int aroff = (wave >> 2) * 8192;       // this wave's A region (lo/hi)
    const int sw0   = ((quad)     ^ (l16 & 7)) << 3;
    const int sw1   = ((quad + 4) ^ (l16 & 7)) << 3;

    // stage-side constants: thread t covers LDS slot t (row t>>3, slot t&7);
    // global chunk q = (t&7) ^ (row&7) so LDS holds chunk q at slot q^(row&7).
    const int r8  = t >> 3;                     // 0..63
    const int qch = (t & 7) ^ (r8 & 7);
    const __hip_bfloat16* aS = A + (size_t)(tileM + r8) * D_ + qch * 8;
    // B packed rows: call0 pr=r8 (rows {0-31,64-95}+eo*32), call1 pr=64+r8
    const size_t rB0 = (size_t)((r8 >> 5) * 64 + (r8 & 31));
    const size_t rB1 = (size_t)(((64 + r8) >> 5) * 64 + ((64 + r8) & 31));
    const __hip_bfloat16* bS = Bt + (size_t)tileN * D_ + qch * 8;

    // prologue: tile0 fully + B_even(t1); retire tile0, keep B_even(t1) in flight
    STG_B(0, 0, 0);
    STG_B(0, 1, 0);
    STG_A(0, 0, 0);
    STG_A(0, 1, 0);
    STG_B(32768, 0, 1);
    WVM2;
    BAR;

    f32x4_t acc[8][4];
#pragma unroll
    for (int i = 0; i < 8; i++)
#pragma unroll
        for (int j = 0; j < 4; j++) acc[i][j] = (f32x4_t){0.f, 0.f, 0.f, 0.f};
    bf16x8_t af[2][4], bfr[2][2];

    const int NIT = (D_ / 64) / 2;              // 16
    for (int it = 0; it < NIT; ++it) {
        const int t1 = 2 * it + 1, t2 = 2 * it + 2, t3 = 2 * it + 3;
        const bool more = (it + 1 < NIT);

        // P1: buf0 (mi0,ni0)
        DSA(0, 0); DSB(0, 0);
        STG_B(32768, 1, t1);
        STG_A(32768, 0, t1);
        BAR; WLGKM; MM(0, 0); BAR;

        // P2: buf0 (mi0,ni1)  [af reused]
        DSB(0, 1);
        STG_A(32768, 1, t1);
        BAR; WLGKM; MM(0, 1); BAR;

        // P3: buf0 (mi1,ni0)
        DSA(0, 1); DSB(0, 0);
        BAR; WLGKM; MM(1, 0); BAR;

        // P4: buf0 (mi1,ni1); counted wait retires tile t1
        DSB(0, 1);
        if (more) { STG_B(0, 0, t2); WVM2; } else { WVM0; }
        BAR; WLGKM; MM(1, 1); BAR;

        // P5: buf1 (mi0,ni0)
        DSA(32768, 0); DSB(32768, 0);
        if (more) { STG_B(0, 1, t2); STG_A(0, 0, t2); }
        BAR; WLGKM; MM(0, 0); BAR;

        // P6: buf1 (mi0,ni1)
        DSB(32768, 1);
        if (more) STG_A(0, 1, t2);
        BAR; WLGKM; MM(0, 1); BAR;

        // P7: buf1 (mi1,ni0)
        DSA(32768, 1); DSB(32768, 0);
        BAR; WLGKM; MM(1, 0); BAR;

        // P8: buf1 (mi1,ni1); counted wait retires tile t2
        DSB(32768, 1);
        if (more) { STG_B(32768, 0, t3); WVM2; } else { WVM0; }
        BAR; WLGKM; MM(1, 1); BAR;
    }

    // epilogue
    const int sel  = by >> 3;                   // 0=q, 1=k, 2=v
    const int nbas = tileN - sel * INNER_;
    if (sel < 2) {
        const float* bias = sel ? bk : bq;
        __hip_bfloat16* C = sel ? ko : qo;
#pragma unroll
        for (int i = 0; i < 8; i++) {
            const int m = tileM + wm + i * 16 + quad * 4;
#pragma unroll
            for (int j = 0; j < 4; j++) {
                const int n = nbas + wn + j * 16 + l16;
                const float bn = bias[n];
#pragma unroll
                for (int r = 0; r < 4; r++)
                    C[(size_t)(m + r) * INNER_ + n] = __float2bfloat16(acc[i][j][r] + bn);
            }
        }
    } else {
        const int bb = tileM >> 11;             // 256-row tile never straddles batch
#pragma unroll
        for (int i = 0; i < 8; i++) {
            const int l0 = (tileM + wm + i * 16 + quad * 4) & (L_ - 1);
#pragma unroll
            for (int j = 0; j < 4; j++) {
                const int n  = nbas + wn + j * 16 + l16;
                const int hh = n >> 7, dd = n & 127;
                const float bvn = bv[n];
                ushort4 pk;
                pk.x = f2bf(acc[i][j][0] + bvn);
                pk.y = f2bf(acc[i][j][1] + bvn);
                pk.z = f2bf(acc[i][j][2] + bvn);
                pk.w = f2bf(acc[i][j][3] + bvn);
                *(ushort4*)(vTo + ((size_t)(bb * H_ + hh) * DH_ + dd) * L_ + l0) = pk;
            }
        }
    }
}

// ---------------------------------------------------------------- RMSNorm + RoPE (q&k fused)
__global__ __launch_bounds__(256)
void k_rmsrope2(__hip_bfloat16* __restrict__ qb, __hip_bfloat16* __restrict__ kb,
                const float* __restrict__ qn, const float* __restrict__ kn,
                const float* __restrict__ pcos, const float* __restrict__ psin,
                const float* __restrict__ lls, float qextra) {
    const int which = blockIdx.y;
    __hip_bfloat16* buf = which ? kb : qb;
    const float* w = which ? kn : qn;
    const int row = blockIdx.x;
    const int l   = row & (L_ - 1);
    const int t   = threadIdx.x;
    __hip_bfloat16* p = buf + (size_t)row * INNER_ + t * 8;

    float x[8];
    {
        const unsigned short* ps = (const unsigned short*)p;
        ushort4 a = *(const ushort4*)ps;
        ushort4 b = *(const ushort4*)(ps + 4);
        unsigned short s[8] = {a.x, a.y, a.z, a.w, b.x, b.y, b.z, b.w};
#pragma unroll
        for (int i = 0; i < 8; i++) x[i] = bf2f(s[i]);
    }
    float ss = 0.f;
#pragma unroll
    for (int i = 0; i < 8; i++) ss += x[i] * x[i];
#pragma unroll
    for (int off = 32; off >= 1; off >>= 1) ss += __shfl_down(ss, off);
    __shared__ float red[4];
    if ((t & 63) == 0) red[t >> 6] = ss;
    __syncthreads();
    ss = red[0] + red[1] + red[2] + red[3];
    const float rstd = rsqrtf(ss * (1.0f / (float)INNER_) + 1e-6f);

    const float scale = which ? 1.0f : (qextra * lls[l]);

    const float4 c4 = ((const float4*)(pcos + (size_t)l * (INNER_ / 2)))[t];
    const float4 s4 = ((const float4*)(psin + (size_t)l * (INNER_ / 2)))[t];
    const float cc[4] = {c4.x, c4.y, c4.z, c4.w};
    const float sn[4] = {s4.x, s4.y, s4.z, s4.w};
    const float4 w0 = ((const float4*)w)[t * 2];
    const float4 w1 = ((const float4*)w)[t * 2 + 1];
    const float ww[8] = {w0.x, w0.y, w0.z, w0.w, w1.x, w1.y, w1.z, w1.w};

    union { __hip_bfloat16 h[8]; uint4 u; } pk;
#pragma unroll
    for (int pi = 0; pi < 4; pi++) {
        const float y1 = x[pi * 2]     * rstd * ww[pi * 2];
        const float y2 = x[pi * 2 + 1] * rstd * ww[pi * 2 + 1];
        pk.h[pi * 2]     = __float2bfloat16((y1 * cc[pi] - y2 * sn[pi]) * scale);
        pk.h[pi * 2 + 1] = __float2bfloat16((y1 * sn[pi] + y2 * cc[pi]) * scale);
    }
    *(uint4*)p = pk.u;
}

// ---------------------------------------------------------------- attention
__global__ __launch_bounds__(512)
void k_attn(const __hip_bfloat16* __restrict__ q,
            const __hip_bfloat16* __restrict__ k,
            const __hip_bfloat16* __restrict__ vT,
            __hip_bfloat16* __restrict__ o) {
    __shared__ __align__(16) __hip_bfloat16 Ks[64 * 128];   // [key][d] swizzled
    __shared__ __align__(16) __hip_bfloat16 Vs[128 * 64];   // [d][key] swizzled
    __shared__ __align__(16) __hip_bfloat16 Pt[8][16 * 72]; // [wave][qrow][key] stride 72

    const int p  = blockIdx.x;   // 0..7
    const int bh = blockIdx.y;
    const int b  = bh >> 4;
    const int h  = bh & 15;
    const int t = threadIdx.x, wave = t >> 6, lane = t & 63;
    const int quad = lane >> 4, l16 = lane & 15;

    const int kr = t >> 4;                          // 0..31
    const int kc = ((t & 15) ^ (kr & 15)) << 3;
    const int vr = t >> 3;                          // 0..63
    const int vc = ((t & 7) ^ (vr & 7)) << 3;
    const __hip_bfloat16* kbase = k  + (size_t)b * L_ * INNER_ + h * DH_;
    const __hip_bfloat16* vbase = vT + (size_t)bh * DH_ * L_;

    for (int half = 0; half < 2; ++half) {
        const int qt = half ? (15 - p) : p;
        const int rowbase = qt * 128 + wave * 16;

        bf16x8_t aq[4];
        {
            const size_t qoff = (size_t)(b * L_ + rowbase + l16) * INNER_ + h * DH_;
#pragma unroll
            for (int kk = 0; kk < 4; kk++)
                aq[kk] = *(const bf16x8_t*)(q + qoff + kk * 32 + quad * 8);
        }

        f32x4_t oacc[8];
#pragma unroll
        for (int jj = 0; jj < 8; jj++) oacc[jj] = (f32x4_t){0.f, 0.f, 0.f, 0.f};
        float m_ = -1e30f, l_ = 0.f;

        const int nkt = 2 * qt + 2;
        for (int kt = 0; kt < nkt; ++kt) {
            const int kv0 = kt * 64;
            __syncthreads();
            gld_lds16(kbase + (size_t)(kv0 + kr)      * INNER_ + kc, &Ks[t * 8]);
            gld_lds16(kbase + (size_t)(kv0 + 32 + kr) * INNER_ + kc, &Ks[4096 + t * 8]);
            gld_lds16(vbase + (size_t)vr        * L_ + kv0 + vc, &Vs[t * 8]);
            gld_lds16(vbase + (size_t)(64 + vr) * L_ + kv0 + vc, &Vs[4096 + t * 8]);
            __syncthreads();

            if (kv0 > rowbase + 15) continue;

            f32x4_t sacc[4];
#pragma unroll
            for (int tt = 0; tt < 4; tt++) sacc[tt] = (f32x4_t){0.f, 0.f, 0.f, 0.f};
#pragma unroll
            for (int kk = 0; kk < 4; kk++) {
                bf16x8_t kf[4];
#pragma unroll
                for (int tt = 0; tt < 4; tt++)
                    kf[tt] = *(const bf16x8_t*)&Ks[(tt * 16 + l16) * 128 + (((kk * 4 + quad) ^ l16) << 3)];
#pragma unroll
                for (int tt = 0; tt < 4; tt++)
                    sacc[tt] = __builtin_amdgcn_mfma_f32_16x16x32_bf16(
                        kf[tt], aq[kk], sacc[tt], 0, 0, 0);
            }

            if (kv0 + 63 > rowbase) {
                const int qrow = rowbase + l16;
#pragma unroll
                for (int tt = 0; tt < 4; tt++)
#pragma unroll
                    for (int r = 0; r < 4; r++)
                        if (kv0 + tt * 16 + quad * 4 + r > qrow) sacc[tt][r] = -1e30f;
            }

            float mx = sacc[0][0];
#pragma unroll
            for (int tt = 0; tt < 4; tt++)
#pragma unroll
                for (int r = 0; r < 4; r++) mx = fmaxf(mx, sacc[tt][r]);
            mx = fmaxf(mx, __shfl_xor(mx, 16));
            mx = fmaxf(mx, __shfl_xor(mx, 32));
            const float mnew = fmaxf(m_, mx);
            const float alpha = exp2f(m_ - mnew);
            m_ = mnew;

            float ls = 0.f;
#pragma unroll
            for (int tt = 0; tt < 4; tt++) {
                ushort4 pk;
                float p0 = exp2f(sacc[tt][0] - mnew);
                float p1 = exp2f(sacc[tt][1] - mnew);
                float p2 = exp2f(sacc[tt][2] - mnew);
                float p3 = exp2f(sacc[tt][3] - mnew);
                ls += (p0 + p1) + (p2 + p3);
                pk.x = f2bf(p0); pk.y = f2bf(p1); pk.z = f2bf(p2); pk.w = f2bf(p3);
                *(ushort4*)&Pt[wave][l16 * 72 + tt * 16 + quad * 4] = pk;
            }
            ls += __shfl_xor(ls, 16);
            ls += __shfl_xor(ls, 32);
            l_ = l_ * alpha + ls;
#pragma unroll
            for (int jj = 0; jj < 8; jj++) {
                oacc[jj][0] *= alpha; oacc[jj][1] *= alpha;
                oacc[jj][2] *= alpha; oacc[jj][3] *= alpha;
            }

#pragma unroll
            for (int kk2 = 0; kk2 < 2; kk2++) {
                bf16x8_t pf = *(const bf16x8_t*)&Pt[wave][l16 * 72 + kk2 * 32 + quad * 8];
#pragma unroll
                for (int jj = 0; jj < 8; jj++) {
                    bf16x8_t vf = *(const bf16x8_t*)
                        &Vs[(jj * 16 + l16) * 64 + (((kk2 * 4 + quad) ^ (l16 & 7)) << 3)];
                    oacc[jj] = __builtin_amdgcn_mfma_f32_16x16x32_bf16(vf, pf, oacc[jj], 0, 0, 0);
                }
            }
        }

        {
            const float inv = 1.0f / l_;
            __hip_bfloat16* orow = o + (size_t)(b * L_ + rowbase + l16) * INNER_ + h * DH_;
#pragma unroll
            for (int jj = 0; jj < 8; jj++) {
                ushort4 pk;
                pk.x = f2bf(oacc[jj][0] * inv);
                pk.y = f2bf(oacc[jj][1] * inv);
                pk.z = f2bf(oacc[jj][2] * inv);
                pk.w = f2bf(oacc[jj][3] * inv);
                *(ushort4*)(orow + jj * 16 + quad * 4) = pk;
            }
        }
    }
}

// ---------------------------------------------------------------- launch
extern "C" void kernel_launch(void* const* d_in, const int* in_sizes, int n_in,
                              void* d_out, int out_size, void* d_ws, size_t ws_size,
                              hipStream_t stream) {
    const float* x      = (const float*)d_in[0];
    const float* pe_cos = (const float*)d_in[1];
    const float* pe_sin = (const float*)d_in[2];
    const float* lls    = (const float*)d_in[3];
    const float* wq     = (const float*)d_in[4];
    const float* bq     = (const float*)d_in[5];
    const float* wk     = (const float*)d_in[6];
    const float* bk     = (const float*)d_in[7];
    const float* wv     = (const float*)d_in[8];
    const float* bv     = (const float*)d_in[9];
    const float* qn     = (const float*)d_in[10];
    const float* kn     = (const float*)d_in[11];
    const float* wo     = (const float*)d_in[12];
    const float* bo     = (const float*)d_in[13];

    char* ws = (char*)d_ws;
    const size_t SZ_W = (size_t)D_ * INNER_ * 2;   // 8 MB (bf16)
    const size_t SZ_M = (size_t)M_ * INNER_ * 2;   // 16 MB (bf16)
    __hip_bfloat16* xb     = (__hip_bfloat16*)ws;  ws += SZ_M;
    __hip_bfloat16* wqkvT  = (__hip_bfloat16*)ws;  ws += 3 * SZ_W;  // [6144][2048]
    __hip_bfloat16* woT    = (__hip_bfloat16*)ws;  ws += SZ_W;
    __hip_bfloat16* qb     = (__hip_bfloat16*)ws;  ws += SZ_M;
    __hip_bfloat16* kb     = (__hip_bfloat16*)ws;  ws += SZ_M;
    __hip_bfloat16* vT     = (__hip_bfloat16*)ws;  ws += SZ_M;
    __hip_bfloat16* ab     = (__hip_bfloat16*)ws;  ws += SZ_M;
    (void)in_sizes; (void)n_in; (void)out_size; (void)ws_size;

    const dim3 tb(256);

    // 0. cast x to bf16
    k_cast<<<(M_ * D_) / 1024, tb, 0, stream>>>(x, (unsigned short*)xb);

    // 1. all 4 weight transpose+casts in one dispatch
    k_wtrans4<<<dim3(64, 64, 4), tb, 0, stream>>>(
        wq, wk, wv, wo,
        (unsigned short*)wqkvT,
        (unsigned short*)(wqkvT + (size_t)INNER_ * D_),
        (unsigned short*)(wqkvT + 2 * (size_t)INNER_ * D_),
        (unsigned short*)woT);

    // 2. fused QKV projection, 256^2 8-phase; v written directly transposed
    k_gemm_qkv<<<dim3(16 * 24), dim3(512), 0, stream>>>(xb, wqkvT, bq, bk, bv, qb, kb, vT);

    // 3. RMSNorm + RoPE for q and k in one dispatch
    const float qextra = 0.08838834764831843f /* rsqrt(128) */ * 1.4426950408889634f /* log2 e */;
    k_rmsrope2<<<dim3(M_, 2), tb, 0, stream>>>(qb, kb, qn, kn, pe_cos, pe_sin, lls, qextra);

    // 4. causal flash attention (S^T formulation, 8 waves/block)
    k_attn<<<dim3(8, B_ * H_), dim3(512), 0, stream>>>(qb, kb, vT, ab);

    // 5. output projection -> d_out (f32)
    k_gemm_bt_f32<<<dim3(M_ / 128, D_ / 128), tb, 0, stream>>>(ab, woT, bo, (float*)d_out, M_, D_, INNER_);
}

// Round 3
// 424.993 us; speedup vs baseline: 1.0568x; 1.0308x over previous
//
#include <hip/hip_runtime.h>
#include <hip/hip_bf16.h>

typedef __bf16 bf16x8_t __attribute__((ext_vector_type(8)));
typedef float  f32x4_t  __attribute__((ext_vector_type(4)));

#define B_     2
#define L_     2048
#define D_     2048
#define H_     16
#define DH_    128
#define INNER_ 2048
#define M_     (B_ * L_)

// async global->LDS, 16B per lane. LDS dest must be wave-uniform base + lane*16.
__device__ __forceinline__ void gld_lds16(const void* g, void* l) {
    __builtin_amdgcn_global_load_lds(
        (const __attribute__((address_space(1))) void*)g,
        (__attribute__((address_space(3))) void*)l,
        16, 0, 0);
}

__device__ __forceinline__ unsigned short f2bf(float f) {
    __hip_bfloat16 h = __float2bfloat16(f);
    return *(unsigned short*)&h;
}
__device__ __forceinline__ float bf2f(unsigned short s) {
    return __uint_as_float(((unsigned)s) << 16);
}

// ---------------------------------------------------------------- cast f32 -> bf16
__global__ __launch_bounds__(256)
void k_cast(const float* __restrict__ in, unsigned short* __restrict__ out) {
    const size_t i = ((size_t)blockIdx.x * 256 + threadIdx.x) * 4;
    float4 v = *(const float4*)(in + i);
    ushort4 o;
    o.x = f2bf(v.x); o.y = f2bf(v.y); o.z = f2bf(v.z); o.w = f2bf(v.w);
    *(ushort4*)(out + i) = o;
}

// ---------------------------------------------------------------- fused 4x transpose+cast
__global__ __launch_bounds__(256)
void k_wtrans4(const float* __restrict__ w0, const float* __restrict__ w1,
               const float* __restrict__ w2, const float* __restrict__ w3,
               unsigned short* __restrict__ d0, unsigned short* __restrict__ d1,
               unsigned short* __restrict__ d2, unsigned short* __restrict__ d3) {
    const int z = blockIdx.z;
    const float* in = (z == 0) ? w0 : (z == 1) ? w1 : (z == 2) ? w2 : w3;
    unsigned short* out = (z == 0) ? d0 : (z == 1) ? d1 : (z == 2) ? d2 : d3;
    __shared__ unsigned short tile[32][33];
    const int t  = threadIdx.x;
    const int r  = t >> 3;
    const int c4 = (t & 7) << 2;
    const size_t ib = ((size_t)blockIdx.y * 32 + r) * 2048 + blockIdx.x * 32 + c4;
    float4 v = *(const float4*)(in + ib);
    tile[r][c4 + 0] = f2bf(v.x); tile[r][c4 + 1] = f2bf(v.y);
    tile[r][c4 + 2] = f2bf(v.z); tile[r][c4 + 3] = f2bf(v.w);
    __syncthreads();
    ushort4 o;
    o.x = tile[c4 + 0][r]; o.y = tile[c4 + 1][r];
    o.z = tile[c4 + 2][r]; o.w = tile[c4 + 3][r];
    const size_t ob = ((size_t)blockIdx.x * 32 + r) * 2048 + blockIdx.y * 32 + c4;
    *(ushort4*)(out + ob) = o;
}

// ---------------------------------------------------------------- GEMM core macro body (128^2, kept for wo-GEMM)
#define GEMM_BODY(A_, Bt_, K_)                                                 \
    __shared__ __align__(16) __hip_bfloat16 As[128 * 32];                      \
    __shared__ __align__(16) __hip_bfloat16 Bs[128 * 32];                      \
    const int t    = threadIdx.x;                                              \
    const int lane = t & 63;                                                   \
    const int wave = t >> 6;                                                   \
    const int quad = lane >> 4;                                                \
    const int l16  = lane & 15;                                                \
    const int wm   = (wave >> 1) * 64;                                         \
    const int wn   = (wave & 1) * 64;                                          \
    const int srow = t >> 2;                                                   \
    const int scol = (t & 3) << 3;                                             \
    const __hip_bfloat16* Ag = A_  + (size_t)(tileM + srow) * K_ + scol;       \
    const __hip_bfloat16* Bg = Bt_ + (size_t)(tileN + srow) * K_ + scol;       \
    __hip_bfloat16* Asl  = &As[t * 8];                                         \
    __hip_bfloat16* Asl2 = &As[2048 + t * 8];                                  \
    __hip_bfloat16* Bsl  = &Bs[t * 8];                                         \
    __hip_bfloat16* Bsl2 = &Bs[2048 + t * 8];                                  \
    const size_t rowskip = (size_t)64 * K_;                                    \
    f32x4_t acc[4][4];                                                         \
    _Pragma("unroll") for (int i = 0; i < 4; i++)                              \
        _Pragma("unroll") for (int j = 0; j < 4; j++)                          \
            acc[i][j] = (f32x4_t){0.f, 0.f, 0.f, 0.f};                         \
    for (int k0 = 0; k0 < K_; k0 += 32) {                                      \
        __syncthreads();                                                       \
        gld_lds16(Ag + k0,           Asl);                                     \
        gld_lds16(Ag + rowskip + k0, Asl2);                                    \
        gld_lds16(Bg + k0,           Bsl);                                     \
        gld_lds16(Bg + rowskip + k0, Bsl2);                                    \
        __syncthreads();                                                       \
        bf16x8_t af[4], bfr[4];                                                \
        _Pragma("unroll") for (int i = 0; i < 4; i++)                          \
            af[i] = *(const bf16x8_t*)&As[(wm + i * 16 + l16) * 32 + quad * 8];\
        _Pragma("unroll") for (int j = 0; j < 4; j++)                          \
            bfr[j] = *(const bf16x8_t*)&Bs[(wn + j * 16 + l16) * 32 + quad * 8];\
        _Pragma("unroll") for (int i = 0; i < 4; i++)                          \
            _Pragma("unroll") for (int j = 0; j < 4; j++)                      \
                acc[i][j] = __builtin_amdgcn_mfma_f32_16x16x32_bf16(           \
                    af[i], bfr[j], acc[i][j], 0, 0, 0);                        \
    }

// wo GEMM: f32 output to d_out
__global__ __launch_bounds__(256)
void k_gemm_bt_f32(const __hip_bfloat16* __restrict__ A,
                   const __hip_bfloat16* __restrict__ Bt,
                   const float* __restrict__ bias,
                   float* __restrict__ C,
                   int M, int N, int K) {
    const int tileM = blockIdx.x * 128;
    const int tileN = blockIdx.y * 128;
    GEMM_BODY(A, Bt, K)
#pragma unroll
    for (int i = 0; i < 4; i++)
#pragma unroll
        for (int r = 0; r < 4; r++) {
            const int m = tileM + wm + i * 16 + quad * 4 + r;
#pragma unroll
            for (int j = 0; j < 4; j++) {
                const int n = tileN + wn + j * 16 + l16;
                C[(size_t)m * N + n] = acc[i][j][r] + bias[n];
            }
        }
}

// ---------------------------------------------------------------- fused QKV GEMM
// 256x192 tile, BK=64, 512 blocks = 2 perfect rounds on 256 CUs.
// 8 waves as 4M x 2N (64x96 per wave, acc[4][6]).
// LDS: A[256][64] double-buffered (@0, @16384 elems),
//      B[192][64] TRIPLE-buffered (@32768 + b*12288 elems) = 136 KiB total.
// Chunk swizzle (T2): 8-elem chunk c of row r stored at slot c^(r&7);
// staged via pre-swizzled GLOBAL source + linear LDS dest (rule 21).
//
// 4 phases per iter (2 K-tiles t=2it, t+1). Stage units: A=4/tile, B=3/tile.
//   Q1 (tile t, mi0): stage A(t+1)u0,u1 -> AB1; B(t+2)u0 -> sb2
//   Q2 (tile t, mi1): stage A(t+1)u2,u3; B(t+2)u1,u2; W_mid = vmcnt(2)
//   Q3 (t+1, mi0):    stage A(t+2)u0,u1 -> AB0; B(t+3)u0 -> sb3(=rb0)
//   Q4 (t+1, mi1):    stage A(t+2)u2,u3; B(t+3)u1,u2; W_end = vmcnt(2)
// FIFO ledger (per wave, steady): leftover 2 youngest B units at each wait;
// retired-before-read verified for every buffer; waits AFTER the MFMA cluster.
#define FENCE asm volatile("" ::: "memory")
#define BAR   do { FENCE; __builtin_amdgcn_s_barrier(); FENCE; } while (0)
#define WLGKM do { asm volatile("s_waitcnt lgkmcnt(0)" ::: "memory");           \
                   __builtin_amdgcn_sched_barrier(0); } while (0)
#define WVM2  asm volatile("s_waitcnt vmcnt(2)" ::: "memory")
#define WVM3  asm volatile("s_waitcnt vmcnt(3)" ::: "memory")
#define WVM0  asm volatile("s_waitcnt vmcnt(0)" ::: "memory")

#define AB0 0
#define AB1 16384
#define BB0 32768

#define QSTG_A(abufe, u, kt)                                                    \
    gld_lds16(aS + ((size_t)(u) * 64) * D_ + (kt) * 64,                         \
              &lds[(abufe) + (u) * 4096 + t * 8])
#define QSTG_B(bbufe, u, kt)                                                    \
    gld_lds16(bS + ((size_t)(u) * 64) * D_ + (kt) * 64,                         \
              &lds[(bbufe) + (u) * 4096 + t * 8])
#define QDSA(abufe, mi) do {                                                    \
    _Pragma("unroll") for (int kk = 0; kk < 2; kk++)                            \
    _Pragma("unroll") for (int i = 0; i < 2; i++)                               \
        af[kk][i] = *(const bf16x8_t*)&lds[(abufe) +                            \
            (wm + (mi) * 32 + i * 16 + l16) * 64 + (kk ? sw1 : sw0)];           \
} while (0)
#define QDSB(bbufe) do {                                                        \
    _Pragma("unroll") for (int kk = 0; kk < 2; kk++)                            \
    _Pragma("unroll") for (int jj = 0; jj < 6; jj++)                            \
        bfr[kk][jj] = *(const bf16x8_t*)&lds[(bbufe) +                          \
            (wn + jj * 16 + l16) * 64 + (kk ? sw1 : sw0)];                      \
} while (0)
#define MMALL(mi) do {                                                          \
    __builtin_amdgcn_s_setprio(1);                                              \
    _Pragma("unroll") for (int kk = 0; kk < 2; kk++)                            \
    _Pragma("unroll") for (int i = 0; i < 2; i++)                               \
    _Pragma("unroll") for (int jj = 0; jj < 6; jj++)                            \
        acc[(mi) * 2 + i][jj] = __builtin_amdgcn_mfma_f32_16x16x32_bf16(        \
            af[kk][i], bfr[kk][jj], acc[(mi) * 2 + i][jj], 0, 0, 0);            \
    __builtin_amdgcn_s_setprio(0);                                              \
} while (0)

__global__ __launch_bounds__(512, 2)
void k_gemm_qkv(const __hip_bfloat16* __restrict__ A,
                const __hip_bfloat16* __restrict__ Bt,
                const float* __restrict__ bq, const float* __restrict__ bk,
                const float* __restrict__ bv,
                __hip_bfloat16* __restrict__ qo, __hip_bfloat16* __restrict__ ko,
                __hip_bfloat16* __restrict__ vTo) {
    __shared__ __align__(16) __hip_bfloat16 lds[69632];  // 136 KiB

    // bijective XCD swizzle (512 % 8 == 0); bx slow within each XCD chunk
    // -> per-XCD A hot-set = 2 MB (L2), B streams from L3 with deep prefetch.
    const int wg = blockIdx.x;
    const int sw = (wg & 7) * 64 + (wg >> 3);
    const int bx = sw >> 5;                    // 16 M-tiles
    const int by = sw & 31;                    // 32 N-tiles
    const int tileM = bx << 8;                 // BM=256
    const int tileN = by * 192;                // BN=192

    const int t    = threadIdx.x;
    const int lane = t & 63;
    const int wave = t >> 6;
    const int quad = lane >> 4;
    const int l16  = lane & 15;
    const int wm   = (wave >> 1) << 6;         // 0/64/128/192
    const int wn   = (wave & 1) * 96;          // 0/96

    const int sw0 = ((quad)     ^ (l16 & 7)) << 3;
    const int sw1 = ((quad + 4) ^ (l16 & 7)) << 3;

    // stage-side: thread t covers rows r8 (per unit), slot t&7 holds global
    // chunk qch = (t&7)^(r8&7)  => LDS slot s of row r holds chunk s^(r&7).
    const int r8  = t >> 3;                    // 0..63
    const int qch = (t & 7) ^ (r8 & 7);
    const __hip_bfloat16* aS = A  + (size_t)(tileM + r8) * D_ + qch * 8;
    const __hip_bfloat16* bS = Bt + (size_t)(tileN + r8) * D_ + qch * 8;

    // prologue: A(0), B(0), B(1); leave B(1) (3 units) in flight
    QSTG_A(AB0, 0, 0); QSTG_A(AB0, 1, 0); QSTG_A(AB0, 2, 0); QSTG_A(AB0, 3, 0);
    QSTG_B(BB0, 0, 0); QSTG_B(BB0, 1, 0); QSTG_B(BB0, 2, 0);
    QSTG_B(BB0 + 12288, 0, 1); QSTG_B(BB0 + 12288, 1, 1); QSTG_B(BB0 + 12288, 2, 1);
    WVM3;
    BAR;

    f32x4_t acc[4][6];
#pragma unroll
    for (int i = 0; i < 4; i++)
#pragma unroll
        for (int j = 0; j < 6; j++) acc[i][j] = (f32x4_t){0.f, 0.f, 0.f, 0.f};
    bf16x8_t af[2][2], bfr[2][6];

    int b0 = 0;                                 // B buffer holding tile 2it
#pragma unroll 1
    for (int it = 0; it < 16; ++it) {
        const bool more = (it < 15);
        const int t1 = 2 * it + 1, t2 = 2 * it + 2, t3 = 2 * it + 3;
        const int b1 = (b0 == 2) ? 0 : b0 + 1;
        const int b2 = (b1 == 2) ? 0 : b1 + 1;
        const int rb0 = BB0 + b0 * 12288;       // B(2it)    read Q1-Q2
        const int rb1 = BB0 + b1 * 12288;       // B(2it+1)  read Q3-Q4
        const int sb2 = BB0 + b2 * 12288;       // B(2it+2)  staged Q1-Q2
        const int sb3 = rb0;                    // B(2it+3)  staged Q3-Q4

        // Q1: tile t, mi0 (rows wm..wm+31)
        QDSA(AB0, 0); QDSB(rb0);
        QSTG_A(AB1, 0, t1); QSTG_A(AB1, 1, t1);
        if (more) QSTG_B(sb2, 0, t2);
        BAR; WLGKM; MMALL(0); BAR;

        // Q2: tile t, mi1
        QDSA(AB0, 1);
        QSTG_A(AB1, 2, t1); QSTG_A(AB1, 3, t1);
        if (more) { QSTG_B(sb2, 1, t2); QSTG_B(sb2, 2, t2); }
        BAR; WLGKM; MMALL(1);
        if (more) { WVM2; } else { WVM0; }      // retire A(t+1), B(t+1)
        BAR;

        // Q3: tile t+1, mi0
        QDSA(AB1, 0); QDSB(rb1);
        if (more) { QSTG_A(AB0, 0, t2); QSTG_A(AB0, 1, t2); QSTG_B(sb3, 0, t3); }
        BAR; WLGKM; MMALL(0); BAR;

        // Q4: tile t+1, mi1
        QDSA(AB1, 1);
        if (more) { QSTG_A(AB0, 2, t2); QSTG_A(AB0, 3, t2);
                    QSTG_B(sb3, 1, t3); QSTG_B(sb3, 2, t3); }
        BAR; WLGKM; MMALL(1);
        if (more) { WVM2; } else { WVM0; }      // retire A(t+2), B(t+2)
        BAR;

        b0 = b2;
    }

    // epilogue: section boundaries (2048,4096) are 16-aligned -> sel is
    // fragment-uniform even though 192 does not divide 2048.
#pragma unroll
    for (int ai = 0; ai < 4; ai++) {
        const int m = tileM + wm + ai * 16 + quad * 4;
#pragma unroll
        for (int bj = 0; bj < 6; bj++) {
            const int n0  = tileN + wn + bj * 16;
            const int sel = n0 >> 11;            // 0=q, 1=k, 2=v
            const int n   = (n0 & (INNER_ - 1)) + l16;
            if (sel < 2) {
                const float* bias = sel ? bk : bq;
                __hip_bfloat16* C = sel ? ko : qo;
                const float bn = bias[n];
#pragma unroll
                for (int r = 0; r < 4; r++)
                    C[(size_t)(m + r) * INNER_ + n] =
                        __float2bfloat16(acc[ai][bj][r] + bn);
            } else {
                const int hh = n >> 7, dd = n & 127;
                const int bb = tileM >> 11;      // 256-row tile never straddles batch
                const int l0 = m & (L_ - 1);
                const float bvn = bv[n];
                ushort4 pk;
                pk.x = f2bf(acc[ai][bj][0] + bvn);
                pk.y = f2bf(acc[ai][bj][1] + bvn);
                pk.z = f2bf(acc[ai][bj][2] + bvn);
                pk.w = f2bf(acc[ai][bj][3] + bvn);
                *(ushort4*)(vTo + ((size_t)(bb * H_ + hh) * DH_ + dd) * L_ + l0) = pk;
            }
        }
    }
}

// ---------------------------------------------------------------- RMSNorm + RoPE (q&k fused)
__global__ __launch_bounds__(256)
void k_rmsrope2(__hip_bfloat16* __restrict__ qb, __hip_bfloat16* __restrict__ kb,
                const float* __restrict__ qn, const float* __restrict__ kn,
                const float* __restrict__ pcos, const float* __restrict__ psin,
                const float* __restrict__ lls, float qextra) {
    const int which = blockIdx.y;
    __hip_bfloat16* buf = which ? kb : qb;
    const float* w = which ? kn : qn;
    const int row = blockIdx.x;
    const int l   = row & (L_ - 1);
    const int t   = threadIdx.x;
    __hip_bfloat16* p = buf + (size_t)row * INNER_ + t * 8;

    float x[8];
    {
        const unsigned short* ps = (const unsigned short*)p;
        ushort4 a = *(const ushort4*)ps;
        ushort4 b = *(const ushort4*)(ps + 4);
        unsigned short s[8] = {a.x, a.y, a.z, a.w, b.x, b.y, b.z, b.w};
#pragma unroll
        for (int i = 0; i < 8; i++) x[i] = bf2f(s[i]);
    }
    float ss = 0.f;
#pragma unroll
    for (int i = 0; i < 8; i++) ss += x[i] * x[i];
#pragma unroll
    for (int off = 32; off >= 1; off >>= 1) ss += __shfl_down(ss, off);
    __shared__ float red[4];
    if ((t & 63) == 0) red[t >> 6] = ss;
    __syncthreads();
    ss = red[0] + red[1] + red[2] + red[3];
    const float rstd = rsqrtf(ss * (1.0f / (float)INNER_) + 1e-6f);

    const float scale = which ? 1.0f : (qextra * lls[l]);

    const float4 c4 = ((const float4*)(pcos + (size_t)l * (INNER_ / 2)))[t];
    const float4 s4 = ((const float4*)(psin + (size_t)l * (INNER_ / 2)))[t];
    const float cc[4] = {c4.x, c4.y, c4.z, c4.w};
    const float sn[4] = {s4.x, s4.y, s4.z, s4.w};
    const float4 w0 = ((const float4*)w)[t * 2];
    const float4 w1 = ((const float4*)w)[t * 2 + 1];
    const float ww[8] = {w0.x, w0.y, w0.z, w0.w, w1.x, w1.y, w1.z, w1.w};

    union { __hip_bfloat16 h[8]; uint4 u; } pk;
#pragma unroll
    for (int pi = 0; pi < 4; pi++) {
        const float y1 = x[pi * 2]     * rstd * ww[pi * 2];
        const float y2 = x[pi * 2 + 1] * rstd * ww[pi * 2 + 1];
        pk.h[pi * 2]     = __float2bfloat16((y1 * cc[pi] - y2 * sn[pi]) * scale);
        pk.h[pi * 2 + 1] = __float2bfloat16((y1 * sn[pi] + y2 * cc[pi]) * scale);
    }
    *(uint4*)p = pk.u;
}

// ---------------------------------------------------------------- attention
__global__ __launch_bounds__(512)
void k_attn(const __hip_bfloat16* __restrict__ q,
            const __hip_bfloat16* __restrict__ k,
            const __hip_bfloat16* __restrict__ vT,
            __hip_bfloat16* __restrict__ o) {
    __shared__ __align__(16) __hip_bfloat16 Ks[64 * 128];   // [key][d] swizzled
    __shared__ __align__(16) __hip_bfloat16 Vs[128 * 64];   // [d][key] swizzled
    __shared__ __align__(16) __hip_bfloat16 Pt[8][16 * 72]; // [wave][qrow][key] stride 72

    const int p  = blockIdx.x;   // 0..7
    const int bh = blockIdx.y;
    const int b  = bh >> 4;
    const int h  = bh & 15;
    const int t = threadIdx.x, wave = t >> 6, lane = t & 63;
    const int quad = lane >> 4, l16 = lane & 15;

    const int kr = t >> 4;                          // 0..31
    const int kc = ((t & 15) ^ (kr & 15)) << 3;
    const int vr = t >> 3;                          // 0..63
    const int vc = ((t & 7) ^ (vr & 7)) << 3;
    const __hip_bfloat16* kbase = k  + (size_t)b * L_ * INNER_ + h * DH_;
    const __hip_bfloat16* vbase = vT + (size_t)bh * DH_ * L_;

    for (int half = 0; half < 2; ++half) {
        const int qt = half ? (15 - p) : p;
        const int rowbase = qt * 128 + wave * 16;

        bf16x8_t aq[4];
        {
            const size_t qoff = (size_t)(b * L_ + rowbase + l16) * INNER_ + h * DH_;
#pragma unroll
            for (int kk = 0; kk < 4; kk++)
                aq[kk] = *(const bf16x8_t*)(q + qoff + kk * 32 + quad * 8);
        }

        f32x4_t oacc[8];
#pragma unroll
        for (int jj = 0; jj < 8; jj++) oacc[jj] = (f32x4_t){0.f, 0.f, 0.f, 0.f};
        float m_ = -1e30f, l_ = 0.f;

        const int nkt = 2 * qt + 2;
        for (int kt = 0; kt < nkt; ++kt) {
            const int kv0 = kt * 64;
            __syncthreads();
            gld_lds16(kbase + (size_t)(kv0 + kr)      * INNER_ + kc, &Ks[t * 8]);
            gld_lds16(kbase + (size_t)(kv0 + 32 + kr) * INNER_ + kc, &Ks[4096 + t * 8]);
            gld_lds16(vbase + (size_t)vr        * L_ + kv0 + vc, &Vs[t * 8]);
            gld_lds16(vbase + (size_t)(64 + vr) * L_ + kv0 + vc, &Vs[4096 + t * 8]);
            __syncthreads();

            if (kv0 > rowbase + 15) continue;

            f32x4_t sacc[4];
#pragma unroll
            for (int tt = 0; tt < 4; tt++) sacc[tt] = (f32x4_t){0.f, 0.f, 0.f, 0.f};
#pragma unroll
            for (int kk = 0; kk < 4; kk++) {
                bf16x8_t kf[4];
#pragma unroll
                for (int tt = 0; tt < 4; tt++)
                    kf[tt] = *(const bf16x8_t*)&Ks[(tt * 16 + l16) * 128 + (((kk * 4 + quad) ^ l16) << 3)];
#pragma unroll
                for (int tt = 0; tt < 4; tt++)
                    sacc[tt] = __builtin_amdgcn_mfma_f32_16x16x32_bf16(
                        kf[tt], aq[kk], sacc[tt], 0, 0, 0);
            }

            if (kv0 + 63 > rowbase) {
                const int qrow = rowbase + l16;
#pragma unroll
                for (int tt = 0; tt < 4; tt++)
#pragma unroll
                    for (int r = 0; r < 4; r++)
                        if (kv0 + tt * 16 + quad * 4 + r > qrow) sacc[tt][r] = -1e30f;
            }

            float mx = sacc[0][0];
#pragma unroll
            for (int tt = 0; tt < 4; tt++)
#pragma unroll
                for (int r = 0; r < 4; r++) mx = fmaxf(mx, sacc[tt][r]);
            mx = fmaxf(mx, __shfl_xor(mx, 16));
            mx = fmaxf(mx, __shfl_xor(mx, 32));
            const float mnew = fmaxf(m_, mx);
            const float alpha = exp2f(m_ - mnew);
            m_ = mnew;

            float ls = 0.f;
#pragma unroll
            for (int tt = 0; tt < 4; tt++) {
                ushort4 pk;
                float p0 = exp2f(sacc[tt][0] - mnew);
                float p1 = exp2f(sacc[tt][1] - mnew);
                float p2 = exp2f(sacc[tt][2] - mnew);
                float p3 = exp2f(sacc[tt][3] - mnew);
                ls += (p0 + p1) + (p2 + p3);
                pk.x = f2bf(p0); pk.y = f2bf(p1); pk.z = f2bf(p2); pk.w = f2bf(p3);
                *(ushort4*)&Pt[wave][l16 * 72 + tt * 16 + quad * 4] = pk;
            }
            ls += __shfl_xor(ls, 16);
            ls += __shfl_xor(ls, 32);
            l_ = l_ * alpha + ls;
#pragma unroll
            for (int jj = 0; jj < 8; jj++) {
                oacc[jj][0] *= alpha; oacc[jj][1] *= alpha;
                oacc[jj][2] *= alpha; oacc[jj][3] *= alpha;
            }

#pragma unroll
            for (int kk2 = 0; kk2 < 2; kk2++) {
                bf16x8_t pf = *(const bf16x8_t*)&Pt[wave][l16 * 72 + kk2 * 32 + quad * 8];
#pragma unroll
                for (int jj = 0; jj < 8; jj++) {
                    bf16x8_t vf = *(const bf16x8_t*)
                        &Vs[(jj * 16 + l16) * 64 + (((kk2 * 4 + quad) ^ (l16 & 7)) << 3)];
                    oacc[jj] = __builtin_amdgcn_mfma_f32_16x16x32_bf16(vf, pf, oacc[jj], 0, 0, 0);
                }
            }
        }

        {
            const float inv = 1.0f / l_;
            __hip_bfloat16* orow = o + (size_t)(b * L_ + rowbase + l16) * INNER_ + h * DH_;
#pragma unroll
            for (int jj = 0; jj < 8; jj++) {
                ushort4 pk;
                pk.x = f2bf(oacc[jj][0] * inv);
                pk.y = f2bf(oacc[jj][1] * inv);
                pk.z = f2bf(oacc[jj][2] * inv);
                pk.w = f2bf(oacc[jj][3] * inv);
                *(ushort4*)(orow + jj * 16 + quad * 4) = pk;
            }
        }
    }
}

// ---------------------------------------------------------------- launch
extern "C" void kernel_launch(void* const* d_in, const int* in_sizes, int n_in,
                              void* d_out, int out_size, void* d_ws, size_t ws_size,
                              hipStream_t stream) {
    const float* x      = (const float*)d_in[0];
    const float* pe_cos = (const float*)d_in[1];
    const float* pe_sin = (const float*)d_in[2];
    const float* lls    = (const float*)d_in[3];
    const float* wq     = (const float*)d_in[4];
    const float* bq     = (const float*)d_in[5];
    const float* wk     = (const float*)d_in[6];
    const float* bk     = (const float*)d_in[7];
    const float* wv     = (const float*)d_in[8];
    const float* bv     = (const float*)d_in[9];
    const float* qn     = (const float*)d_in[10];
    const float* kn     = (const float*)d_in[11];
    const float* wo     = (const float*)d_in[12];
    const float* bo     = (const float*)d_in[13];

    char* ws = (char*)d_ws;
    const size_t SZ_W = (size_t)D_ * INNER_ * 2;   // 8 MB (bf16)
    const size_t SZ_M = (size_t)M_ * INNER_ * 2;   // 16 MB (bf16)
    __hip_bfloat16* xb     = (__hip_bfloat16*)ws;  ws += SZ_M;
    __hip_bfloat16* wqkvT  = (__hip_bfloat16*)ws;  ws += 3 * SZ_W;  // [6144][2048]
    __hip_bfloat16* woT    = (__hip_bfloat16*)ws;  ws += SZ_W;
    __hip_bfloat16* qb     = (__hip_bfloat16*)ws;  ws += SZ_M;
    __hip_bfloat16* kb     = (__hip_bfloat16*)ws;  ws += SZ_M;
    __hip_bfloat16* vT     = (__hip_bfloat16*)ws;  ws += SZ_M;
    __hip_bfloat16* ab     = (__hip_bfloat16*)ws;  ws += SZ_M;
    (void)in_sizes; (void)n_in; (void)out_size; (void)ws_size;

    const dim3 tb(256);

    // 0. cast x to bf16
    k_cast<<<(M_ * D_) / 1024, tb, 0, stream>>>(x, (unsigned short*)xb);

    // 1. all 4 weight transpose+casts in one dispatch
    k_wtrans4<<<dim3(64, 64, 4), tb, 0, stream>>>(
        wq, wk, wv, wo,
        (unsigned short*)wqkvT,
        (unsigned short*)(wqkvT + (size_t)INNER_ * D_),
        (unsigned short*)(wqkvT + 2 * (size_t)INNER_ * D_),
        (unsigned short*)woT);

    // 2. fused QKV projection, 256x192 deep-pipelined; v written directly transposed
    k_gemm_qkv<<<dim3(512), dim3(512), 0, stream>>>(xb, wqkvT, bq, bk, bv, qb, kb, vT);

    // 3. RMSNorm + RoPE for q and k in one dispatch
    const float qextra = 0.08838834764831843f /* rsqrt(128) */ * 1.4426950408889634f /* log2 e */;
    k_rmsrope2<<<dim3(M_, 2), tb, 0, stream>>>(qb, kb, qn, kn, pe_cos, pe_sin, lls, qextra);

    // 4. causal flash attention (S^T formulation, 8 waves/block)
    k_attn<<<dim3(8, B_ * H_), dim3(512), 0, stream>>>(qb, kb, vT, ab);

    // 5. output projection -> d_out (f32)
    k_gemm_bt_f32<<<dim3(M_ / 128, D_ / 128), tb, 0, stream>>>(ab, woT, bo, (float*)d_out, M_, D_, INNER_);
}

// Round 4
// 424.205 us; speedup vs baseline: 1.0587x; 1.0019x over previous
//
#include <hip/hip_runtime.h>
#include <hip/hip_bf16.h>

typedef __bf16 bf16x8_t __attribute__((ext_vector_type(8)));
typedef float  f32x4_t  __attribute__((ext_vector_type(4)));

#define B_     2
#define L_     2048
#define D_     2048
#define H_     16
#define DH_    128
#define INNER_ 2048
#define M_     (B_ * L_)

// async global->LDS, 16B per lane. LDS dest must be wave-uniform base + lane*16.
__device__ __forceinline__ void gld_lds16(const void* g, void* l) {
    __builtin_amdgcn_global_load_lds(
        (const __attribute__((address_space(1))) void*)g,
        (__attribute__((address_space(3))) void*)l,
        16, 0, 0);
}

__device__ __forceinline__ unsigned short f2bf(float f) {
    __hip_bfloat16 h = __float2bfloat16(f);
    return *(unsigned short*)&h;
}
__device__ __forceinline__ float bf2f(unsigned short s) {
    return __uint_as_float(((unsigned)s) << 16);
}

// ---------------------------------------------------------------- cast f32 -> bf16
__global__ __launch_bounds__(256)
void k_cast(const float* __restrict__ in, unsigned short* __restrict__ out) {
    const size_t i = ((size_t)blockIdx.x * 256 + threadIdx.x) * 4;
    float4 v = *(const float4*)(in + i);
    ushort4 o;
    o.x = f2bf(v.x); o.y = f2bf(v.y); o.z = f2bf(v.z); o.w = f2bf(v.w);
    *(ushort4*)(out + i) = o;
}

// ---------------------------------------------------------------- fused 4x transpose+cast
__global__ __launch_bounds__(256)
void k_wtrans4(const float* __restrict__ w0, const float* __restrict__ w1,
               const float* __restrict__ w2, const float* __restrict__ w3,
               unsigned short* __restrict__ d0, unsigned short* __restrict__ d1,
               unsigned short* __restrict__ d2, unsigned short* __restrict__ d3) {
    const int z = blockIdx.z;
    const float* in = (z == 0) ? w0 : (z == 1) ? w1 : (z == 2) ? w2 : w3;
    unsigned short* out = (z == 0) ? d0 : (z == 1) ? d1 : (z == 2) ? d2 : d3;
    __shared__ unsigned short tile[32][33];
    const int t  = threadIdx.x;
    const int r  = t >> 3;
    const int c4 = (t & 7) << 2;
    const size_t ib = ((size_t)blockIdx.y * 32 + r) * 2048 + blockIdx.x * 32 + c4;
    float4 v = *(const float4*)(in + ib);
    tile[r][c4 + 0] = f2bf(v.x); tile[r][c4 + 1] = f2bf(v.y);
    tile[r][c4 + 2] = f2bf(v.z); tile[r][c4 + 3] = f2bf(v.w);
    __syncthreads();
    ushort4 o;
    o.x = tile[c4 + 0][r]; o.y = tile[c4 + 1][r];
    o.z = tile[c4 + 2][r]; o.w = tile[c4 + 3][r];
    const size_t ob = ((size_t)blockIdx.x * 32 + r) * 2048 + blockIdx.y * 32 + c4;
    *(ushort4*)(out + ob) = o;
}

// ---------------------------------------------------------------- GEMM core macro body (128^2, kept for wo-GEMM)
#define GEMM_BODY(A_, Bt_, K_)                                                 \
    __shared__ __align__(16) __hip_bfloat16 As[128 * 32];                      \
    __shared__ __align__(16) __hip_bfloat16 Bs[128 * 32];                      \
    const int t    = threadIdx.x;                                              \
    const int lane = t & 63;                                                   \
    const int wave = t >> 6;                                                   \
    const int quad = lane >> 4;                                                \
    const int l16  = lane & 15;                                                \
    const int wm   = (wave >> 1) * 64;                                         \
    const int wn   = (wave & 1) * 64;                                          \
    const int srow = t >> 2;                                                   \
    const int scol = (t & 3) << 3;                                             \
    const __hip_bfloat16* Ag = A_  + (size_t)(tileM + srow) * K_ + scol;       \
    const __hip_bfloat16* Bg = Bt_ + (size_t)(tileN + srow) * K_ + scol;       \
    __hip_bfloat16* Asl  = &As[t * 8];                                         \
    __hip_bfloat16* Asl2 = &As[2048 + t * 8];                                  \
    __hip_bfloat16* Bsl  = &Bs[t * 8];                                         \
    __hip_bfloat16* Bsl2 = &Bs[2048 + t * 8];                                  \
    const size_t rowskip = (size_t)64 * K_;                                    \
    f32x4_t acc[4][4];                                                         \
    _Pragma("unroll") for (int i = 0; i < 4; i++)                              \
        _Pragma("unroll") for (int j = 0; j < 4; j++)                          \
            acc[i][j] = (f32x4_t){0.f, 0.f, 0.f, 0.f};                         \
    for (int k0 = 0; k0 < K_; k0 += 32) {                                      \
        __syncthreads();                                                       \
        gld_lds16(Ag + k0,           Asl);                                     \
        gld_lds16(Ag + rowskip + k0, Asl2);                                    \
        gld_lds16(Bg + k0,           Bsl);                                     \
        gld_lds16(Bg + rowskip + k0, Bsl2);                                    \
        __syncthreads();                                                       \
        bf16x8_t af[4], bfr[4];                                                \
        _Pragma("unroll") for (int i = 0; i < 4; i++)                          \
            af[i] = *(const bf16x8_t*)&As[(wm + i * 16 + l16) * 32 + quad * 8];\
        _Pragma("unroll") for (int j = 0; j < 4; j++)                          \
            bfr[j] = *(const bf16x8_t*)&Bs[(wn + j * 16 + l16) * 32 + quad * 8];\
        _Pragma("unroll") for (int i = 0; i < 4; i++)                          \
            _Pragma("unroll") for (int j = 0; j < 4; j++)                      \
                acc[i][j] = __builtin_amdgcn_mfma_f32_16x16x32_bf16(           \
                    af[i], bfr[j], acc[i][j], 0, 0, 0);                        \
    }

// wo GEMM: f32 output to d_out
__global__ __launch_bounds__(256)
void k_gemm_bt_f32(const __hip_bfloat16* __restrict__ A,
                   const __hip_bfloat16* __restrict__ Bt,
                   const float* __restrict__ bias,
                   float* __restrict__ C,
                   int M, int N, int K) {
    const int tileM = blockIdx.x * 128;
    const int tileN = blockIdx.y * 128;
    GEMM_BODY(A, Bt, K)
#pragma unroll
    for (int i = 0; i < 4; i++)
#pragma unroll
        for (int r = 0; r < 4; r++) {
            const int m = tileM + wm + i * 16 + quad * 4 + r;
#pragma unroll
            for (int j = 0; j < 4; j++) {
                const int n = tileN + wn + j * 16 + l16;
                C[(size_t)m * N + n] = acc[i][j][r] + bias[n];
            }
        }
}

// ---------------------------------------------------------------- fused QKV GEMM
// 256x192 tile, BK=64, 512 blocks = 2 perfect rounds on 256 CUs.
// 8 waves as 4M x 2N (64x96 per wave, acc[4][6]).
// LDS: A[256][64] double-buffered (@0, @16384 elems),
//      B[192][64] TRIPLE-buffered (@32768 + b*12288 elems) = 136 KiB total.
// Chunk swizzle (T2): 8-elem chunk c of row r stored at slot c^(r&7);
// staged via pre-swizzled GLOBAL source + linear LDS dest (rule 21).
//
// AGED-WAIT schedule (fixes round-3's 0-phase wait aging). Per K-tile t:
//   Ph_a: read A(t) mi0 + B(t) full; stage A(t+1)x4, B(t+2)u0,u1; BAR; MMALL(0); BAR
//   Ph_b: read A(t) mi1; stage B(t+2)u2; BAR; MMALL(1); vmcnt(3); BAR
// Issue stream: [A(t+1)x4, B(t+2)u0,u1][B(t+2)u2] -> at the vmcnt(3) the
// youngest waited load is A(t+1)u3 (1.5 phases old, ~450cy); B(t+1) units are
// 2.5-3.5 phases old (~750cy, covers L3/HBM). One wait per 48 MFMA.
// Prologue: A(0)x4,B(0)x3,B(1)x3; vmcnt(3). Tail: it=30 vmcnt(0); it=31 none.
// Steady invariant at loop top of tile t: outstanding = B(t+1)x3.
#define FENCE asm volatile("" ::: "memory")
#define BAR   do { FENCE; __builtin_amdgcn_s_barrier(); FENCE; } while (0)
#define WLGKM do { asm volatile("s_waitcnt lgkmcnt(0)" ::: "memory");           \
                   __builtin_amdgcn_sched_barrier(0); } while (0)
#define WVM3  asm volatile("s_waitcnt vmcnt(3)" ::: "memory")
#define WVM0  asm volatile("s_waitcnt vmcnt(0)" ::: "memory")

#define AB0 0
#define AB1 16384
#define BB0 32768

#define QSTG_A(abufe, u, kt)                                                    \
    gld_lds16(aS + ((size_t)(u) * 64) * D_ + (kt) * 64,                         \
              &lds[(abufe) + (u) * 4096 + t * 8])
#define QSTG_B(bbufe, u, kt)                                                    \
    gld_lds16(bS + ((size_t)(u) * 64) * D_ + (kt) * 64,                         \
              &lds[(bbufe) + (u) * 4096 + t * 8])
#define QDSA(abufe, mi) do {                                                    \
    _Pragma("unroll") for (int kk = 0; kk < 2; kk++)                            \
    _Pragma("unroll") for (int i = 0; i < 2; i++)                               \
        af[kk][i] = *(const bf16x8_t*)&lds[(abufe) +                            \
            (wm + (mi) * 32 + i * 16 + l16) * 64 + (kk ? sw1 : sw0)];           \
} while (0)
#define QDSB(bbufe) do {                                                        \
    _Pragma("unroll") for (int kk = 0; kk < 2; kk++)                            \
    _Pragma("unroll") for (int jj = 0; jj < 6; jj++)                            \
        bfr[kk][jj] = *(const bf16x8_t*)&lds[(bbufe) +                          \
            (wn + jj * 16 + l16) * 64 + (kk ? sw1 : sw0)];                      \
} while (0)
#define MMALL(mi) do {                                                          \
    __builtin_amdgcn_s_setprio(1);                                              \
    _Pragma("unroll") for (int kk = 0; kk < 2; kk++)                            \
    _Pragma("unroll") for (int i = 0; i < 2; i++)                               \
    _Pragma("unroll") for (int jj = 0; jj < 6; jj++)                            \
        acc[(mi) * 2 + i][jj] = __builtin_amdgcn_mfma_f32_16x16x32_bf16(        \
            af[kk][i], bfr[kk][jj], acc[(mi) * 2 + i][jj], 0, 0, 0);            \
    __builtin_amdgcn_s_setprio(0);                                              \
} while (0)

__global__ __launch_bounds__(512, 2)
void k_gemm_qkv(const __hip_bfloat16* __restrict__ A,
                const __hip_bfloat16* __restrict__ Bt,
                const float* __restrict__ bq, const float* __restrict__ bk,
                const float* __restrict__ bv,
                __hip_bfloat16* __restrict__ qo, __hip_bfloat16* __restrict__ ko,
                __hip_bfloat16* __restrict__ vTo) {
    __shared__ __align__(16) __hip_bfloat16 lds[69632];  // 136 KiB

    // bijective XCD swizzle (512 % 8 == 0); bx slow within each XCD chunk
    // -> per-XCD A hot-set = 2 MB (L2), B streams from L3 with deep prefetch.
    const int wg = blockIdx.x;
    const int sw = (wg & 7) * 64 + (wg >> 3);
    const int bx = sw >> 5;                    // 16 M-tiles
    const int by = sw & 31;                    // 32 N-tiles
    const int tileM = bx << 8;                 // BM=256
    const int tileN = by * 192;                // BN=192

    const int t    = threadIdx.x;
    const int lane = t & 63;
    const int wave = t >> 6;
    const int quad = lane >> 4;
    const int l16  = lane & 15;
    const int wm   = (wave >> 1) << 6;         // 0/64/128/192
    const int wn   = (wave & 1) * 96;          // 0/96

    const int sw0 = ((quad)     ^ (l16 & 7)) << 3;
    const int sw1 = ((quad + 4) ^ (l16 & 7)) << 3;

    // stage-side: thread t covers rows r8 (per unit), slot t&7 holds global
    // chunk qch = (t&7)^(r8&7)  => LDS slot s of row r holds chunk s^(r&7).
    const int r8  = t >> 3;                    // 0..63
    const int qch = (t & 7) ^ (r8 & 7);
    const __hip_bfloat16* aS = A  + (size_t)(tileM + r8) * D_ + qch * 8;
    const __hip_bfloat16* bS = Bt + (size_t)(tileN + r8) * D_ + qch * 8;

    // prologue: A(0)x4, B(0)x3, B(1)x3; retire A(0),B(0); leave B(1) in flight
    QSTG_A(AB0, 0, 0); QSTG_A(AB0, 1, 0); QSTG_A(AB0, 2, 0); QSTG_A(AB0, 3, 0);
    QSTG_B(BB0, 0, 0); QSTG_B(BB0, 1, 0); QSTG_B(BB0, 2, 0);
    QSTG_B(BB0 + 12288, 0, 1); QSTG_B(BB0 + 12288, 1, 1); QSTG_B(BB0 + 12288, 2, 1);
    WVM3;
    BAR;

    f32x4_t acc[4][6];
#pragma unroll
    for (int i = 0; i < 4; i++)
#pragma unroll
        for (int j = 0; j < 6; j++) acc[i][j] = (f32x4_t){0.f, 0.f, 0.f, 0.f};
    bf16x8_t af[2][2], bfr[2][6];

    int rbm = 0;                                // B buffer of tile it
    int sbm = 2;                                // B buffer for tile it+2
#pragma unroll 1
    for (int it = 0; it < 32; ++it) {
        const int ra = (it & 1) ? AB1 : AB0;    // A(it)
        const int sa = (it & 1) ? AB0 : AB1;    // A(it+1) dest
        const int rb = BB0 + rbm * 12288;       // B(it)
        const int sb = BB0 + sbm * 12288;       // B(it+2) dest
        const bool stA = (it + 1 < 32);
        const bool stB = (it + 2 < 32);

        // Ph_a: mi0; stage all of A(it+1) + B(it+2)u0,u1
        QDSA(ra, 0); QDSB(rb);
        if (stA) { QSTG_A(sa, 0, it + 1); QSTG_A(sa, 1, it + 1);
                   QSTG_A(sa, 2, it + 1); QSTG_A(sa, 3, it + 1); }
        if (stB) { QSTG_B(sb, 0, it + 2); QSTG_B(sb, 1, it + 2); }
        BAR; WLGKM; MMALL(0); BAR;

        // Ph_b: mi1; stage B(it+2)u2; single aged wait per K-tile
        QDSA(ra, 1);
        if (stB) QSTG_B(sb, 2, it + 2);
        BAR; WLGKM; MMALL(1);
        if (stB) { WVM3; } else if (stA) { WVM0; }
        BAR;

        rbm = (rbm == 2) ? 0 : rbm + 1;
        sbm = (sbm == 2) ? 0 : sbm + 1;
    }

    // epilogue: section boundaries (2048,4096) are 16-aligned -> sel is
    // fragment-uniform even though 192 does not divide 2048.
#pragma unroll
    for (int ai = 0; ai < 4; ai++) {
        const int m = tileM + wm + ai * 16 + quad * 4;
#pragma unroll
        for (int bj = 0; bj < 6; bj++) {
            const int n0  = tileN + wn + bj * 16;
            const int sel = n0 >> 11;            // 0=q, 1=k, 2=v
            const int n   = (n0 & (INNER_ - 1)) + l16;
            if (sel < 2) {
                const float* bias = sel ? bk : bq;
                __hip_bfloat16* C = sel ? ko : qo;
                const float bn = bias[n];
#pragma unroll
                for (int r = 0; r < 4; r++)
                    C[(size_t)(m + r) * INNER_ + n] =
                        __float2bfloat16(acc[ai][bj][r] + bn);
            } else {
                const int hh = n >> 7, dd = n & 127;
                const int bb = tileM >> 11;      // 256-row tile never straddles batch
                const int l0 = m & (L_ - 1);
                const float bvn = bv[n];
                ushort4 pk;
                pk.x = f2bf(acc[ai][bj][0] + bvn);
                pk.y = f2bf(acc[ai][bj][1] + bvn);
                pk.z = f2bf(acc[ai][bj][2] + bvn);
                pk.w = f2bf(acc[ai][bj][3] + bvn);
                *(ushort4*)(vTo + ((size_t)(bb * H_ + hh) * DH_ + dd) * L_ + l0) = pk;
            }
        }
    }
}

// ---------------------------------------------------------------- RMSNorm + RoPE (q&k fused)
__global__ __launch_bounds__(256)
void k_rmsrope2(__hip_bfloat16* __restrict__ qb, __hip_bfloat16* __restrict__ kb,
                const float* __restrict__ qn, const float* __restrict__ kn,
                const float* __restrict__ pcos, const float* __restrict__ psin,
                const float* __restrict__ lls, float qextra) {
    const int which = blockIdx.y;
    __hip_bfloat16* buf = which ? kb : qb;
    const float* w = which ? kn : qn;
    const int row = blockIdx.x;
    const int l   = row & (L_ - 1);
    const int t   = threadIdx.x;
    __hip_bfloat16* p = buf + (size_t)row * INNER_ + t * 8;

    float x[8];
    {
        const unsigned short* ps = (const unsigned short*)p;
        ushort4 a = *(const ushort4*)ps;
        ushort4 b = *(const ushort4*)(ps + 4);
        unsigned short s[8] = {a.x, a.y, a.z, a.w, b.x, b.y, b.z, b.w};
#pragma unroll
        for (int i = 0; i < 8; i++) x[i] = bf2f(s[i]);
    }
    float ss = 0.f;
#pragma unroll
    for (int i = 0; i < 8; i++) ss += x[i] * x[i];
#pragma unroll
    for (int off = 32; off >= 1; off >>= 1) ss += __shfl_down(ss, off);
    __shared__ float red[4];
    if ((t & 63) == 0) red[t >> 6] = ss;
    __syncthreads();
    ss = red[0] + red[1] + red[2] + red[3];
    const float rstd = rsqrtf(ss * (1.0f / (float)INNER_) + 1e-6f);

    const float scale = which ? 1.0f : (qextra * lls[l]);

    const float4 c4 = ((const float4*)(pcos + (size_t)l * (INNER_ / 2)))[t];
    const float4 s4 = ((const float4*)(psin + (size_t)l * (INNER_ / 2)))[t];
    const float cc[4] = {c4.x, c4.y, c4.z, c4.w};
    const float sn[4] = {s4.x, s4.y, s4.z, s4.w};
    const float4 w0 = ((const float4*)w)[t * 2];
    const float4 w1 = ((const float4*)w)[t * 2 + 1];
    const float ww[8] = {w0.x, w0.y, w0.z, w0.w, w1.x, w1.y, w1.z, w1.w};

    union { __hip_bfloat16 h[8]; uint4 u; } pk;
#pragma unroll
    for (int pi = 0; pi < 4; pi++) {
        const float y1 = x[pi * 2]     * rstd * ww[pi * 2];
        const float y2 = x[pi * 2 + 1] * rstd * ww[pi * 2 + 1];
        pk.h[pi * 2]     = __float2bfloat16((y1 * cc[pi] - y2 * sn[pi]) * scale);
        pk.h[pi * 2 + 1] = __float2bfloat16((y1 * sn[pi] + y2 * cc[pi]) * scale);
    }
    *(uint4*)p = pk.u;
}

// ---------------------------------------------------------------- attention
__global__ __launch_bounds__(512)
void k_attn(const __hip_bfloat16* __restrict__ q,
            const __hip_bfloat16* __restrict__ k,
            const __hip_bfloat16* __restrict__ vT,
            __hip_bfloat16* __restrict__ o) {
    __shared__ __align__(16) __hip_bfloat16 Ks[64 * 128];   // [key][d] swizzled
    __shared__ __align__(16) __hip_bfloat16 Vs[128 * 64];   // [d][key] swizzled
    __shared__ __align__(16) __hip_bfloat16 Pt[8][16 * 72]; // [wave][qrow][key] stride 72

    const int p  = blockIdx.x;   // 0..7
    const int bh = blockIdx.y;
    const int b  = bh >> 4;
    const int h  = bh & 15;
    const int t = threadIdx.x, wave = t >> 6, lane = t & 63;
    const int quad = lane >> 4, l16 = lane & 15;

    const int kr = t >> 4;                          // 0..31
    const int kc = ((t & 15) ^ (kr & 15)) << 3;
    const int vr = t >> 3;                          // 0..63
    const int vc = ((t & 7) ^ (vr & 7)) << 3;
    const __hip_bfloat16* kbase = k  + (size_t)b * L_ * INNER_ + h * DH_;
    const __hip_bfloat16* vbase = vT + (size_t)bh * DH_ * L_;

    for (int half = 0; half < 2; ++half) {
        const int qt = half ? (15 - p) : p;
        const int rowbase = qt * 128 + wave * 16;

        bf16x8_t aq[4];
        {
            const size_t qoff = (size_t)(b * L_ + rowbase + l16) * INNER_ + h * DH_;
#pragma unroll
            for (int kk = 0; kk < 4; kk++)
                aq[kk] = *(const bf16x8_t*)(q + qoff + kk * 32 + quad * 8);
        }

        f32x4_t oacc[8];
#pragma unroll
        for (int jj = 0; jj < 8; jj++) oacc[jj] = (f32x4_t){0.f, 0.f, 0.f, 0.f};
        float m_ = -1e30f, l_ = 0.f;

        const int nkt = 2 * qt + 2;
        for (int kt = 0; kt < nkt; ++kt) {
            const int kv0 = kt * 64;
            __syncthreads();
            gld_lds16(kbase + (size_t)(kv0 + kr)      * INNER_ + kc, &Ks[t * 8]);
            gld_lds16(kbase + (size_t)(kv0 + 32 + kr) * INNER_ + kc, &Ks[4096 + t * 8]);
            gld_lds16(vbase + (size_t)vr        * L_ + kv0 + vc, &Vs[t * 8]);
            gld_lds16(vbase + (size_t)(64 + vr) * L_ + kv0 + vc, &Vs[4096 + t * 8]);
            __syncthreads();

            if (kv0 > rowbase + 15) continue;

            f32x4_t sacc[4];
#pragma unroll
            for (int tt = 0; tt < 4; tt++) sacc[tt] = (f32x4_t){0.f, 0.f, 0.f, 0.f};
#pragma unroll
            for (int kk = 0; kk < 4; kk++) {
                bf16x8_t kf[4];
#pragma unroll
                for (int tt = 0; tt < 4; tt++)
                    kf[tt] = *(const bf16x8_t*)&Ks[(tt * 16 + l16) * 128 + (((kk * 4 + quad) ^ l16) << 3)];
#pragma unroll
                for (int tt = 0; tt < 4; tt++)
                    sacc[tt] = __builtin_amdgcn_mfma_f32_16x16x32_bf16(
                        kf[tt], aq[kk], sacc[tt], 0, 0, 0);
            }

            if (kv0 + 63 > rowbase) {
                const int qrow = rowbase + l16;
#pragma unroll
                for (int tt = 0; tt < 4; tt++)
#pragma unroll
                    for (int r = 0; r < 4; r++)
                        if (kv0 + tt * 16 + quad * 4 + r > qrow) sacc[tt][r] = -1e30f;
            }

            float mx = sacc[0][0];
#pragma unroll
            for (int tt = 0; tt < 4; tt++)
#pragma unroll
                for (int r = 0; r < 4; r++) mx = fmaxf(mx, sacc[tt][r]);
            mx = fmaxf(mx, __shfl_xor(mx, 16));
            mx = fmaxf(mx, __shfl_xor(mx, 32));
            const float mnew = fmaxf(m_, mx);
            const float alpha = exp2f(m_ - mnew);
            m_ = mnew;

            float ls = 0.f;
#pragma unroll
            for (int tt = 0; tt < 4; tt++) {
                ushort4 pk;
                float p0 = exp2f(sacc[tt][0] - mnew);
                float p1 = exp2f(sacc[tt][1] - mnew);
                float p2 = exp2f(sacc[tt][2] - mnew);
                float p3 = exp2f(sacc[tt][3] - mnew);
                ls += (p0 + p1) + (p2 + p3);
                pk.x = f2bf(p0); pk.y = f2bf(p1); pk.z = f2bf(p2); pk.w = f2bf(p3);
                *(ushort4*)&Pt[wave][l16 * 72 + tt * 16 + quad * 4] = pk;
            }
            ls += __shfl_xor(ls, 16);
            ls += __shfl_xor(ls, 32);
            l_ = l_ * alpha + ls;
#pragma unroll
            for (int jj = 0; jj < 8; jj++) {
                oacc[jj][0] *= alpha; oacc[jj][1] *= alpha;
                oacc[jj][2] *= alpha; oacc[jj][3] *= alpha;
            }

#pragma unroll
            for (int kk2 = 0; kk2 < 2; kk2++) {
                bf16x8_t pf = *(const bf16x8_t*)&Pt[wave][l16 * 72 + kk2 * 32 + quad * 8];
#pragma unroll
                for (int jj = 0; jj < 8; jj++) {
                    bf16x8_t vf = *(const bf16x8_t*)
                        &Vs[(jj * 16 + l16) * 64 + (((kk2 * 4 + quad) ^ (l16 & 7)) << 3)];
                    oacc[jj] = __builtin_amdgcn_mfma_f32_16x16x32_bf16(vf, pf, oacc[jj], 0, 0, 0);
                }
            }
        }

        {
            const float inv = 1.0f / l_;
            __hip_bfloat16* orow = o + (size_t)(b * L_ + rowbase + l16) * INNER_ + h * DH_;
#pragma unroll
            for (int jj = 0; jj < 8; jj++) {
                ushort4 pk;
                pk.x = f2bf(oacc[jj][0] * inv);
                pk.y = f2bf(oacc[jj][1] * inv);
                pk.z = f2bf(oacc[jj][2] * inv);
                pk.w = f2bf(oacc[jj][3] * inv);
                *(ushort4*)(orow + jj * 16 + quad * 4) = pk;
            }
        }
    }
}

// ---------------------------------------------------------------- launch
extern "C" void kernel_launch(void* const* d_in, const int* in_sizes, int n_in,
                              void* d_out, int out_size, void* d_ws, size_t ws_size,
                              hipStream_t stream) {
    const float* x      = (const float*)d_in[0];
    const float* pe_cos = (const float*)d_in[1];
    const float* pe_sin = (const float*)d_in[2];
    const float* lls    = (const float*)d_in[3];
    const float* wq     = (const float*)d_in[4];
    const float* bq     = (const float*)d_in[5];
    const float* wk     = (const float*)d_in[6];
    const float* bk     = (const float*)d_in[7];
    const float* wv     = (const float*)d_in[8];
    const float* bv     = (const float*)d_in[9];
    const float* qn     = (const float*)d_in[10];
    const float* kn     = (const float*)d_in[11];
    const float* wo     = (const float*)d_in[12];
    const float* bo     = (const float*)d_in[13];

    char* ws = (char*)d_ws;
    const size_t SZ_W = (size_t)D_ * INNER_ * 2;   // 8 MB (bf16)
    const size_t SZ_M = (size_t)M_ * INNER_ * 2;   // 16 MB (bf16)
    __hip_bfloat16* xb     = (__hip_bfloat16*)ws;  ws += SZ_M;
    __hip_bfloat16* wqkvT  = (__hip_bfloat16*)ws;  ws += 3 * SZ_W;  // [6144][2048]
    __hip_bfloat16* woT    = (__hip_bfloat16*)ws;  ws += SZ_W;
    __hip_bfloat16* qb     = (__hip_bfloat16*)ws;  ws += SZ_M;
    __hip_bfloat16* kb     = (__hip_bfloat16*)ws;  ws += SZ_M;
    __hip_bfloat16* vT     = (__hip_bfloat16*)ws;  ws += SZ_M;
    __hip_bfloat16* ab     = (__hip_bfloat16*)ws;  ws += SZ_M;
    (void)in_sizes; (void)n_in; (void)out_size; (void)ws_size;

    const dim3 tb(256);

    // 0. cast x to bf16
    k_cast<<<(M_ * D_) / 1024, tb, 0, stream>>>(x, (unsigned short*)xb);

    // 1. all 4 weight transpose+casts in one dispatch
    k_wtrans4<<<dim3(64, 64, 4), tb, 0, stream>>>(
        wq, wk, wv, wo,
        (unsigned short*)wqkvT,
        (unsigned short*)(wqkvT + (size_t)INNER_ * D_),
        (unsigned short*)(wqkvT + 2 * (size_t)INNER_ * D_),
        (unsigned short*)woT);

    // 2. fused QKV projection, 256x192 aged-wait pipeline; v written transposed
    k_gemm_qkv<<<dim3(512), dim3(512), 0, stream>>>(xb, wqkvT, bq, bk, bv, qb, kb, vT);

    // 3. RMSNorm + RoPE for q and k in one dispatch
    const float qextra = 0.08838834764831843f /* rsqrt(128) */ * 1.4426950408889634f /* log2 e */;
    k_rmsrope2<<<dim3(M_, 2), tb, 0, stream>>>(qb, kb, qn, kn, pe_cos, pe_sin, lls, qextra);

    // 4. causal flash attention (S^T formulation, 8 waves/block)
    k_attn<<<dim3(8, B_ * H_), dim3(512), 0, stream>>>(qb, kb, vT, ab);

    // 5. output projection -> d_out (f32)
    k_gemm_bt_f32<<<dim3(M_ / 128, D_ / 128), tb, 0, stream>>>(ab, woT, bo, (float*)d_out, M_, D_, INNER_);
}

// Round 5
// 420.104 us; speedup vs baseline: 1.0691x; 1.0098x over previous
//
#include <hip/hip_runtime.h>
#include <hip/hip_bf16.h>

typedef __bf16 bf16x8_t __attribute__((ext_vector_type(8)));
typedef float  f32x4_t  __attribute__((ext_vector_type(4)));

#define B_     2
#define L_     2048
#define D_     2048
#define H_     16
#define DH_    128
#define INNER_ 2048
#define M_     (B_ * L_)

// async global->LDS, 16B per lane. LDS dest must be wave-uniform base + lane*16.
__device__ __forceinline__ void gld_lds16(const void* g, void* l) {
    __builtin_amdgcn_global_load_lds(
        (const __attribute__((address_space(1))) void*)g,
        (__attribute__((address_space(3))) void*)l,
        16, 0, 0);
}

__device__ __forceinline__ unsigned short f2bf(float f) {
    __hip_bfloat16 h = __float2bfloat16(f);
    return *(unsigned short*)&h;
}
__device__ __forceinline__ float bf2f(unsigned short s) {
    return __uint_as_float(((unsigned)s) << 16);
}

// ---------------------------------------------------------------- cast f32 -> bf16
__global__ __launch_bounds__(256)
void k_cast(const float* __restrict__ in, unsigned short* __restrict__ out) {
    const size_t i = ((size_t)blockIdx.x * 256 + threadIdx.x) * 4;
    float4 v = *(const float4*)(in + i);
    ushort4 o;
    o.x = f2bf(v.x); o.y = f2bf(v.y); o.z = f2bf(v.z); o.w = f2bf(v.w);
    *(ushort4*)(out + i) = o;
}

// ---------------------------------------------------------------- fused 4x transpose+cast
__global__ __launch_bounds__(256)
void k_wtrans4(const float* __restrict__ w0, const float* __restrict__ w1,
               const float* __restrict__ w2, const float* __restrict__ w3,
               unsigned short* __restrict__ d0, unsigned short* __restrict__ d1,
               unsigned short* __restrict__ d2, unsigned short* __restrict__ d3) {
    const int z = blockIdx.z;
    const float* in = (z == 0) ? w0 : (z == 1) ? w1 : (z == 2) ? w2 : w3;
    unsigned short* out = (z == 0) ? d0 : (z == 1) ? d1 : (z == 2) ? d2 : d3;
    __shared__ unsigned short tile[32][33];
    const int t  = threadIdx.x;
    const int r  = t >> 3;
    const int c4 = (t & 7) << 2;
    const size_t ib = ((size_t)blockIdx.y * 32 + r) * 2048 + blockIdx.x * 32 + c4;
    float4 v = *(const float4*)(in + ib);
    tile[r][c4 + 0] = f2bf(v.x); tile[r][c4 + 1] = f2bf(v.y);
    tile[r][c4 + 2] = f2bf(v.z); tile[r][c4 + 3] = f2bf(v.w);
    __syncthreads();
    ushort4 o;
    o.x = tile[c4 + 0][r]; o.y = tile[c4 + 1][r];
    o.z = tile[c4 + 2][r]; o.w = tile[c4 + 3][r];
    const size_t ob = ((size_t)blockIdx.x * 32 + r) * 2048 + blockIdx.y * 32 + c4;
    *(ushort4*)(out + ob) = o;
}

// ---------------------------------------------------------------- GEMM core macro body (128^2, kept for wo-GEMM)
#define GEMM_BODY(A_, Bt_, K_)                                                 \
    __shared__ __align__(16) __hip_bfloat16 As[128 * 32];                      \
    __shared__ __align__(16) __hip_bfloat16 Bs[128 * 32];                      \
    const int t    = threadIdx.x;                                              \
    const int lane = t & 63;                                                   \
    const int wave = t >> 6;                                                   \
    const int quad = lane >> 4;                                                \
    const int l16  = lane & 15;                                                \
    const int wm   = (wave >> 1) * 64;                                         \
    const int wn   = (wave & 1) * 64;                                          \
    const int srow = t >> 2;                                                   \
    const int scol = (t & 3) << 3;                                             \
    const __hip_bfloat16* Ag = A_  + (size_t)(tileM + srow) * K_ + scol;       \
    const __hip_bfloat16* Bg = Bt_ + (size_t)(tileN + srow) * K_ + scol;       \
    __hip_bfloat16* Asl  = &As[t * 8];                                         \
    __hip_bfloat16* Asl2 = &As[2048 + t * 8];                                  \
    __hip_bfloat16* Bsl  = &Bs[t * 8];                                         \
    __hip_bfloat16* Bsl2 = &Bs[2048 + t * 8];                                  \
    const size_t rowskip = (size_t)64 * K_;                                    \
    f32x4_t acc[4][4];                                                         \
    _Pragma("unroll") for (int i = 0; i < 4; i++)                              \
        _Pragma("unroll") for (int j = 0; j < 4; j++)                          \
            acc[i][j] = (f32x4_t){0.f, 0.f, 0.f, 0.f};                         \
    for (int k0 = 0; k0 < K_; k0 += 32) {                                      \
        __syncthreads();                                                       \
        gld_lds16(Ag + k0,           Asl);                                     \
        gld_lds16(Ag + rowskip + k0, Asl2);                                    \
        gld_lds16(Bg + k0,           Bsl);                                     \
        gld_lds16(Bg + rowskip + k0, Bsl2);                                    \
        __syncthreads();                                                       \
        bf16x8_t af[4], bfr[4];                                                \
        _Pragma("unroll") for (int i = 0; i < 4; i++)                          \
            af[i] = *(const bf16x8_t*)&As[(wm + i * 16 + l16) * 32 + quad * 8];\
        _Pragma("unroll") for (int j = 0; j < 4; j++)                          \
            bfr[j] = *(const bf16x8_t*)&Bs[(wn + j * 16 + l16) * 32 + quad * 8];\
        _Pragma("unroll") for (int i = 0; i < 4; i++)                          \
            _Pragma("unroll") for (int j = 0; j < 4; j++)                      \
                acc[i][j] = __builtin_amdgcn_mfma_f32_16x16x32_bf16(           \
                    af[i], bfr[j], acc[i][j], 0, 0, 0);                        \
    }

// wo GEMM: f32 output to d_out
__global__ __launch_bounds__(256)
void k_gemm_bt_f32(const __hip_bfloat16* __restrict__ A,
                   const __hip_bfloat16* __restrict__ Bt,
                   const float* __restrict__ bias,
                   float* __restrict__ C,
                   int M, int N, int K) {
    const int tileM = blockIdx.x * 128;
    const int tileN = blockIdx.y * 128;
    GEMM_BODY(A, Bt, K)
#pragma unroll
    for (int i = 0; i < 4; i++)
#pragma unroll
        for (int r = 0; r < 4; r++) {
            const int m = tileM + wm + i * 16 + quad * 4 + r;
#pragma unroll
            for (int j = 0; j < 4; j++) {
                const int n = tileN + wn + j * 16 + l16;
                C[(size_t)m * N + n] = acc[i][j][r] + bias[n];
            }
        }
}

// ---------------------------------------------------------------- fused QKV GEMM
// 256x192 tile, BK=64, 512 blocks = 2 perfect rounds on 256 CUs (1 block/CU,
// forced by 136 KiB LDS). 8 waves as 4M x 2N (64x96 per wave, acc[4][6]).
// LDS: A[256][64] double-buffered (@0, @16384 elems),
//      B[192][64] TRIPLE-buffered (@32768 + b*12288 elems) = 136 KiB total.
// Chunk swizzle (T2): 8-elem chunk c of row r stored at slot c^(r&7);
// staged via pre-swizzled GLOBAL source + linear LDS dest (rule 21).
//
// SINGLE-BARRIER K-tile body (round-5 change): per K-tile t:
//   [stage A(t+1)x4 -> sa, B(t+2)x3 -> sb]   (issued first: max vmem aging)
//   [ds_read all 20 b128 + 48 MFMA, COMPILER-managed lgkmcnt(N) interleave]
//   vmcnt(3); s_barrier                       (retires A(t+1)+B(t+1); B(t+2) flies)
// No forced lgkmcnt(0), no mid-phase barriers -> ds_read streams under MFMA
// within a wave AND across the 2 waves/SIMD (4 barriers/K-tile -> 1).
// Hazard ledger (same as round 4, re-verified): every staged buffer was last
// read before the PREVIOUS end-barrier (WAR ok); every read buffer was staged
// 1-2 tiles earlier, vmcnt-retired at the previous end-wait, barrier-crossed
// (RAW ok). Prologue: A(0)x4,B(0)x3,B(1)x3; vmcnt(3). Tail: it=30 vmcnt(0).
#define FENCE asm volatile("" ::: "memory")
#define BAR   do { FENCE; __builtin_amdgcn_s_barrier(); FENCE; } while (0)
#define WVM3  asm volatile("s_waitcnt vmcnt(3)" ::: "memory")
#define WVM0  asm volatile("s_waitcnt vmcnt(0)" ::: "memory")

#define AB0 0
#define AB1 16384
#define BB0 32768

#define QSTG_A(abufe, u, kt)                                                    \
    gld_lds16(aS + ((size_t)(u) * 64) * D_ + (kt) * 64,                         \
              &lds[(abufe) + (u) * 4096 + t * 8])
#define QSTG_B(bbufe, u, kt)                                                    \
    gld_lds16(bS + ((size_t)(u) * 64) * D_ + (kt) * 64,                         \
              &lds[(bbufe) + (u) * 4096 + t * 8])
#define QDSA2(abufe) do {                                                       \
    _Pragma("unroll") for (int mi = 0; mi < 2; mi++)                            \
    _Pragma("unroll") for (int kk = 0; kk < 2; kk++)                            \
    _Pragma("unroll") for (int i = 0; i < 2; i++)                               \
        af[mi][kk][i] = *(const bf16x8_t*)&lds[(abufe) +                        \
            (wm + mi * 32 + i * 16 + l16) * 64 + (kk ? sw1 : sw0)];             \
} while (0)
#define QDSB(bbufe) do {                                                        \
    _Pragma("unroll") for (int kk = 0; kk < 2; kk++)                            \
    _Pragma("unroll") for (int jj = 0; jj < 6; jj++)                            \
        bfr[kk][jj] = *(const bf16x8_t*)&lds[(bbufe) +                          \
            (wn + jj * 16 + l16) * 64 + (kk ? sw1 : sw0)];                      \
} while (0)
#define MMALL2 do {                                                             \
    __builtin_amdgcn_s_setprio(1);                                              \
    _Pragma("unroll") for (int mi = 0; mi < 2; mi++)                            \
    _Pragma("unroll") for (int kk = 0; kk < 2; kk++)                            \
    _Pragma("unroll") for (int i = 0; i < 2; i++)                               \
    _Pragma("unroll") for (int jj = 0; jj < 6; jj++)                            \
        acc[mi * 2 + i][jj] = __builtin_amdgcn_mfma_f32_16x16x32_bf16(          \
            af[mi][kk][i], bfr[kk][jj], acc[mi * 2 + i][jj], 0, 0, 0);          \
    __builtin_amdgcn_s_setprio(0);                                              \
} while (0)

__global__ __launch_bounds__(512, 2)
void k_gemm_qkv(const __hip_bfloat16* __restrict__ A,
                const __hip_bfloat16* __restrict__ Bt,
                const float* __restrict__ bq, const float* __restrict__ bk,
                const float* __restrict__ bv,
                __hip_bfloat16* __restrict__ qo, __hip_bfloat16* __restrict__ ko,
                __hip_bfloat16* __restrict__ vTo) {
    __shared__ __align__(16) __hip_bfloat16 lds[69632];  // 136 KiB

    // bijective XCD swizzle: each XCD owns an 8bx x 8by region (by-fast).
    // Per-XCD unique footprint: A 8 MB + B 6 MB (was 2+24 with bx-slow) ->
    // predicted FETCH 205 -> ~115-140 MB; concurrent round hot-set fits L2.
    const int wg   = blockIdx.x;
    const int xcd  = wg & 7;
    const int loc  = wg >> 3;                  // 0..63
    const int bx   = ((xcd & 1) << 3) + (loc & 7);    // 16 M-tiles
    const int by   = ((xcd >> 1) << 3) + (loc >> 3);  // 32 N-tiles
    const int tileM = bx << 8;                 // BM=256
    const int tileN = by * 192;                // BN=192

    const int t    = threadIdx.x;
    const int lane = t & 63;
    const int wave = t >> 6;
    const int quad = lane >> 4;
    const int l16  = lane & 15;
    const int wm   = (wave >> 1) << 6;         // 0/64/128/192
    const int wn   = (wave & 1) * 96;          // 0/96

    const int sw0 = ((quad)     ^ (l16 & 7)) << 3;
    const int sw1 = ((quad + 4) ^ (l16 & 7)) << 3;

    // stage-side: thread t covers rows r8 (per unit), slot t&7 holds global
    // chunk qch = (t&7)^(r8&7)  => LDS slot s of row r holds chunk s^(r&7).
    const int r8  = t >> 3;                    // 0..63
    const int qch = (t & 7) ^ (r8 & 7);
    const __hip_bfloat16* aS = A  + (size_t)(tileM + r8) * D_ + qch * 8;
    const __hip_bfloat16* bS = Bt + (size_t)(tileN + r8) * D_ + qch * 8;

    // prologue: A(0)x4, B(0)x3, B(1)x3; retire A(0),B(0); leave B(1) in flight
    QSTG_A(AB0, 0, 0); QSTG_A(AB0, 1, 0); QSTG_A(AB0, 2, 0); QSTG_A(AB0, 3, 0);
    QSTG_B(BB0, 0, 0); QSTG_B(BB0, 1, 0); QSTG_B(BB0, 2, 0);
    QSTG_B(BB0 + 12288, 0, 1); QSTG_B(BB0 + 12288, 1, 1); QSTG_B(BB0 + 12288, 2, 1);
    WVM3;
    BAR;

    f32x4_t acc[4][6];
#pragma unroll
    for (int i = 0; i < 4; i++)
#pragma unroll
        for (int j = 0; j < 6; j++) acc[i][j] = (f32x4_t){0.f, 0.f, 0.f, 0.f};
    bf16x8_t af[2][2][2], bfr[2][6];

    int rbm = 0;                                // B buffer of tile it
    int sbm = 2;                                // B buffer for tile it+2
#pragma unroll 1
    for (int it = 0; it < 32; ++it) {
        const int ra = (it & 1) ? AB1 : AB0;    // A(it)
        const int sa = (it & 1) ? AB0 : AB1;    // A(it+1) dest
        const int rb = BB0 + rbm * 12288;       // B(it)
        const int sb = BB0 + sbm * 12288;       // B(it+2) dest
        const bool stA = (it + 1 < 32);
        const bool stB = (it + 2 < 32);

        // stage first (max vmem aging across the whole MFMA body)
        if (stA) { QSTG_A(sa, 0, it + 1); QSTG_A(sa, 1, it + 1);
                   QSTG_A(sa, 2, it + 1); QSTG_A(sa, 3, it + 1); }
        if (stB) { QSTG_B(sb, 0, it + 2); QSTG_B(sb, 1, it + 2);
                   QSTG_B(sb, 2, it + 2); }

        // all reads + all MFMAs, compiler-interleaved (fine-grained lgkmcnt)
        QDSA2(ra);
        QDSB(rb);
        MMALL2;

        if (stB) { WVM3; } else if (stA) { WVM0; }
        BAR;

        rbm = (rbm == 2) ? 0 : rbm + 1;
        sbm = (sbm == 2) ? 0 : sbm + 1;
    }

    // epilogue: section boundaries (2048,4096) are 16-aligned -> sel is
    // fragment-uniform even though 192 does not divide 2048.
#pragma unroll
    for (int ai = 0; ai < 4; ai++) {
        const int m = tileM + wm + ai * 16 + quad * 4;
#pragma unroll
        for (int bj = 0; bj < 6; bj++) {
            const int n0  = tileN + wn + bj * 16;
            const int sel = n0 >> 11;            // 0=q, 1=k, 2=v
            const int n   = (n0 & (INNER_ - 1)) + l16;
            if (sel < 2) {
                const float* bias = sel ? bk : bq;
                __hip_bfloat16* C = sel ? ko : qo;
                const float bn = bias[n];
#pragma unroll
                for (int r = 0; r < 4; r++)
                    C[(size_t)(m + r) * INNER_ + n] =
                        __float2bfloat16(acc[ai][bj][r] + bn);
            } else {
                const int hh = n >> 7, dd = n & 127;
                const int bb = tileM >> 11;      // 256-row tile never straddles batch
                const int l0 = m & (L_ - 1);
                const float bvn = bv[n];
                ushort4 pk;
                pk.x = f2bf(acc[ai][bj][0] + bvn);
                pk.y = f2bf(acc[ai][bj][1] + bvn);
                pk.z = f2bf(acc[ai][bj][2] + bvn);
                pk.w = f2bf(acc[ai][bj][3] + bvn);
                *(ushort4*)(vTo + ((size_t)(bb * H_ + hh) * DH_ + dd) * L_ + l0) = pk;
            }
        }
    }
}

// ---------------------------------------------------------------- RMSNorm + RoPE (q&k fused)
__global__ __launch_bounds__(256)
void k_rmsrope2(__hip_bfloat16* __restrict__ qb, __hip_bfloat16* __restrict__ kb,
                const float* __restrict__ qn, const float* __restrict__ kn,
                const float* __restrict__ pcos, const float* __restrict__ psin,
                const float* __restrict__ lls, float qextra) {
    const int which = blockIdx.y;
    __hip_bfloat16* buf = which ? kb : qb;
    const float* w = which ? kn : qn;
    const int row = blockIdx.x;
    const int l   = row & (L_ - 1);
    const int t   = threadIdx.x;
    __hip_bfloat16* p = buf + (size_t)row * INNER_ + t * 8;

    float x[8];
    {
        const unsigned short* ps = (const unsigned short*)p;
        ushort4 a = *(const ushort4*)ps;
        ushort4 b = *(const ushort4*)(ps + 4);
        unsigned short s[8] = {a.x, a.y, a.z, a.w, b.x, b.y, b.z, b.w};
#pragma unroll
        for (int i = 0; i < 8; i++) x[i] = bf2f(s[i]);
    }
    float ss = 0.f;
#pragma unroll
    for (int i = 0; i < 8; i++) ss += x[i] * x[i];
#pragma unroll
    for (int off = 32; off >= 1; off >>= 1) ss += __shfl_down(ss, off);
    __shared__ float red[4];
    if ((t & 63) == 0) red[t >> 6] = ss;
    __syncthreads();
    ss = red[0] + red[1] + red[2] + red[3];
    const float rstd = rsqrtf(ss * (1.0f / (float)INNER_) + 1e-6f);

    const float scale = which ? 1.0f : (qextra * lls[l]);

    const float4 c4 = ((const float4*)(pcos + (size_t)l * (INNER_ / 2)))[t];
    const float4 s4 = ((const float4*)(psin + (size_t)l * (INNER_ / 2)))[t];
    const float cc[4] = {c4.x, c4.y, c4.z, c4.w};
    const float sn[4] = {s4.x, s4.y, s4.z, s4.w};
    const float4 w0 = ((const float4*)w)[t * 2];
    const float4 w1 = ((const float4*)w)[t * 2 + 1];
    const float ww[8] = {w0.x, w0.y, w0.z, w0.w, w1.x, w1.y, w1.z, w1.w};

    union { __hip_bfloat16 h[8]; uint4 u; } pk;
#pragma unroll
    for (int pi = 0; pi < 4; pi++) {
        const float y1 = x[pi * 2]     * rstd * ww[pi * 2];
        const float y2 = x[pi * 2 + 1] * rstd * ww[pi * 2 + 1];
        pk.h[pi * 2]     = __float2bfloat16((y1 * cc[pi] - y2 * sn[pi]) * scale);
        pk.h[pi * 2 + 1] = __float2bfloat16((y1 * sn[pi] + y2 * cc[pi]) * scale);
    }
    *(uint4*)p = pk.u;
}

// ---------------------------------------------------------------- attention
__global__ __launch_bounds__(512)
void k_attn(const __hip_bfloat16* __restrict__ q,
            const __hip_bfloat16* __restrict__ k,
            const __hip_bfloat16* __restrict__ vT,
            __hip_bfloat16* __restrict__ o) {
    __shared__ __align__(16) __hip_bfloat16 Ks[64 * 128];   // [key][d] swizzled
    __shared__ __align__(16) __hip_bfloat16 Vs[128 * 64];   // [d][key] swizzled
    __shared__ __align__(16) __hip_bfloat16 Pt[8][16 * 72]; // [wave][qrow][key] stride 72

    const int p  = blockIdx.x;   // 0..7
    const int bh = blockIdx.y;
    const int b  = bh >> 4;
    const int h  = bh & 15;
    const int t = threadIdx.x, wave = t >> 6, lane = t & 63;
    const int quad = lane >> 4, l16 = lane & 15;

    const int kr = t >> 4;                          // 0..31
    const int kc = ((t & 15) ^ (kr & 15)) << 3;
    const int vr = t >> 3;                          // 0..63
    const int vc = ((t & 7) ^ (vr & 7)) << 3;
    const __hip_bfloat16* kbase = k  + (size_t)b * L_ * INNER_ + h * DH_;
    const __hip_bfloat16* vbase = vT + (size_t)bh * DH_ * L_;

    for (int half = 0; half < 2; ++half) {
        const int qt = half ? (15 - p) : p;
        const int rowbase = qt * 128 + wave * 16;

        bf16x8_t aq[4];
        {
            const size_t qoff = (size_t)(b * L_ + rowbase + l16) * INNER_ + h * DH_;
#pragma unroll
            for (int kk = 0; kk < 4; kk++)
                aq[kk] = *(const bf16x8_t*)(q + qoff + kk * 32 + quad * 8);
        }

        f32x4_t oacc[8];
#pragma unroll
        for (int jj = 0; jj < 8; jj++) oacc[jj] = (f32x4_t){0.f, 0.f, 0.f, 0.f};
        float m_ = -1e30f, l_ = 0.f;

        const int nkt = 2 * qt + 2;
        for (int kt = 0; kt < nkt; ++kt) {
            const int kv0 = kt * 64;
            __syncthreads();
            gld_lds16(kbase + (size_t)(kv0 + kr)      * INNER_ + kc, &Ks[t * 8]);
            gld_lds16(kbase + (size_t)(kv0 + 32 + kr) * INNER_ + kc, &Ks[4096 + t * 8]);
            gld_lds16(vbase + (size_t)vr        * L_ + kv0 + vc, &Vs[t * 8]);
            gld_lds16(vbase + (size_t)(64 + vr) * L_ + kv0 + vc, &Vs[4096 + t * 8]);
            __syncthreads();

            if (kv0 > rowbase + 15) continue;

            f32x4_t sacc[4];
#pragma unroll
            for (int tt = 0; tt < 4; tt++) sacc[tt] = (f32x4_t){0.f, 0.f, 0.f, 0.f};
#pragma unroll
            for (int kk = 0; kk < 4; kk++) {
                bf16x8_t kf[4];
#pragma unroll
                for (int tt = 0; tt < 4; tt++)
                    kf[tt] = *(const bf16x8_t*)&Ks[(tt * 16 + l16) * 128 + (((kk * 4 + quad) ^ l16) << 3)];
#pragma unroll
                for (int tt = 0; tt < 4; tt++)
                    sacc[tt] = __builtin_amdgcn_mfma_f32_16x16x32_bf16(
                        kf[tt], aq[kk], sacc[tt], 0, 0, 0);
            }

            if (kv0 + 63 > rowbase) {
                const int qrow = rowbase + l16;
#pragma unroll
                for (int tt = 0; tt < 4; tt++)
#pragma unroll
                    for (int r = 0; r < 4; r++)
                        if (kv0 + tt * 16 + quad * 4 + r > qrow) sacc[tt][r] = -1e30f;
            }

            float mx = sacc[0][0];
#pragma unroll
            for (int tt = 0; tt < 4; tt++)
#pragma unroll
                for (int r = 0; r < 4; r++) mx = fmaxf(mx, sacc[tt][r]);
            mx = fmaxf(mx, __shfl_xor(mx, 16));
            mx = fmaxf(mx, __shfl_xor(mx, 32));
            const float mnew = fmaxf(m_, mx);
            const float alpha = exp2f(m_ - mnew);
            m_ = mnew;

            float ls = 0.f;
#pragma unroll
            for (int tt = 0; tt < 4; tt++) {
                ushort4 pk;
                float p0 = exp2f(sacc[tt][0] - mnew);
                float p1 = exp2f(sacc[tt][1] - mnew);
                float p2 = exp2f(sacc[tt][2] - mnew);
                float p3 = exp2f(sacc[tt][3] - mnew);
                ls += (p0 + p1) + (p2 + p3);
                pk.x = f2bf(p0); pk.y = f2bf(p1); pk.z = f2bf(p2); pk.w = f2bf(p3);
                *(ushort4*)&Pt[wave][l16 * 72 + tt * 16 + quad * 4] = pk;
            }
            ls += __shfl_xor(ls, 16);
            ls += __shfl_xor(ls, 32);
            l_ = l_ * alpha + ls;
#pragma unroll
            for (int jj = 0; jj < 8; jj++) {
                oacc[jj][0] *= alpha; oacc[jj][1] *= alpha;
                oacc[jj][2] *= alpha; oacc[jj][3] *= alpha;
            }

#pragma unroll
            for (int kk2 = 0; kk2 < 2; kk2++) {
                bf16x8_t pf = *(const bf16x8_t*)&Pt[wave][l16 * 72 + kk2 * 32 + quad * 8];
#pragma unroll
                for (int jj = 0; jj < 8; jj++) {
                    bf16x8_t vf = *(const bf16x8_t*)
                        &Vs[(jj * 16 + l16) * 64 + (((kk2 * 4 + quad) ^ (l16 & 7)) << 3)];
                    oacc[jj] = __builtin_amdgcn_mfma_f32_16x16x32_bf16(vf, pf, oacc[jj], 0, 0, 0);
                }
            }
        }

        {
            const float inv = 1.0f / l_;
            __hip_bfloat16* orow = o + (size_t)(b * L_ + rowbase + l16) * INNER_ + h * DH_;
#pragma unroll
            for (int jj = 0; jj < 8; jj++) {
                ushort4 pk;
                pk.x = f2bf(oacc[jj][0] * inv);
                pk.y = f2bf(oacc[jj][1] * inv);
                pk.z = f2bf(oacc[jj][2] * inv);
                pk.w = f2bf(oacc[jj][3] * inv);
                *(ushort4*)(orow + jj * 16 + quad * 4) = pk;
            }
        }
    }
}

// ---------------------------------------------------------------- launch
extern "C" void kernel_launch(void* const* d_in, const int* in_sizes, int n_in,
                              void* d_out, int out_size, void* d_ws, size_t ws_size,
                              hipStream_t stream) {
    const float* x      = (const float*)d_in[0];
    const float* pe_cos = (const float*)d_in[1];
    const float* pe_sin = (const float*)d_in[2];
    const float* lls    = (const float*)d_in[3];
    const float* wq     = (const float*)d_in[4];
    const float* bq     = (const float*)d_in[5];
    const float* wk     = (const float*)d_in[6];
    const float* bk     = (const float*)d_in[7];
    const float* wv     = (const float*)d_in[8];
    const float* bv     = (const float*)d_in[9];
    const float* qn     = (const float*)d_in[10];
    const float* kn     = (const float*)d_in[11];
    const float* wo     = (const float*)d_in[12];
    const float* bo     = (const float*)d_in[13];

    char* ws = (char*)d_ws;
    const size_t SZ_W = (size_t)D_ * INNER_ * 2;   // 8 MB (bf16)
    const size_t SZ_M = (size_t)M_ * INNER_ * 2;   // 16 MB (bf16)
    __hip_bfloat16* xb     = (__hip_bfloat16*)ws;  ws += SZ_M;
    __hip_bfloat16* wqkvT  = (__hip_bfloat16*)ws;  ws += 3 * SZ_W;  // [6144][2048]
    __hip_bfloat16* woT    = (__hip_bfloat16*)ws;  ws += SZ_W;
    __hip_bfloat16* qb     = (__hip_bfloat16*)ws;  ws += SZ_M;
    __hip_bfloat16* kb     = (__hip_bfloat16*)ws;  ws += SZ_M;
    __hip_bfloat16* vT     = (__hip_bfloat16*)ws;  ws += SZ_M;
    __hip_bfloat16* ab     = (__hip_bfloat16*)ws;  ws += SZ_M;
    (void)in_sizes; (void)n_in; (void)out_size; (void)ws_size;

    const dim3 tb(256);

    // 0. cast x to bf16
    k_cast<<<(M_ * D_) / 1024, tb, 0, stream>>>(x, (unsigned short*)xb);

    // 1. all 4 weight transpose+casts in one dispatch
    k_wtrans4<<<dim3(64, 64, 4), tb, 0, stream>>>(
        wq, wk, wv, wo,
        (unsigned short*)wqkvT,
        (unsigned short*)(wqkvT + (size_t)INNER_ * D_),
        (unsigned short*)(wqkvT + 2 * (size_t)INNER_ * D_),
        (unsigned short*)woT);

    // 2. fused QKV projection, 256x192 single-barrier pipeline; v transposed
    k_gemm_qkv<<<dim3(512), dim3(512), 0, stream>>>(xb, wqkvT, bq, bk, bv, qb, kb, vT);

    // 3. RMSNorm + RoPE for q and k in one dispatch
    const float qextra = 0.08838834764831843f /* rsqrt(128) */ * 1.4426950408889634f /* log2 e */;
    k_rmsrope2<<<dim3(M_, 2), tb, 0, stream>>>(qb, kb, qn, kn, pe_cos, pe_sin, lls, qextra);

    // 4. causal flash attention (S^T formulation, 8 waves/block)
    k_attn<<<dim3(8, B_ * H_), dim3(512), 0, stream>>>(qb, kb, vT, ab);

    // 5. output projection -> d_out (f32)
    k_gemm_bt_f32<<<dim3(M_ / 128, D_ / 128), tb, 0, stream>>>(ab, woT, bo, (float*)d_out, M_, D_, INNER_);
}

// Round 6
// 405.920 us; speedup vs baseline: 1.1064x; 1.0349x over previous
//
#include <hip/hip_runtime.h>
#include <hip/hip_bf16.h>

typedef __bf16 bf16x8_t __attribute__((ext_vector_type(8)));
typedef float  f32x4_t  __attribute__((ext_vector_type(4)));

#define B_     2
#define L_     2048
#define D_     2048
#define H_     16
#define DH_    128
#define INNER_ 2048
#define M_     (B_ * L_)

// async global->LDS, 16B per lane. LDS dest must be wave-uniform base + lane*16.
__device__ __forceinline__ void gld_lds16(const void* g, void* l) {
    __builtin_amdgcn_global_load_lds(
        (const __attribute__((address_space(1))) void*)g,
        (__attribute__((address_space(3))) void*)l,
        16, 0, 0);
}

__device__ __forceinline__ unsigned short f2bf(float f) {
    __hip_bfloat16 h = __float2bfloat16(f);
    return *(unsigned short*)&h;
}
__device__ __forceinline__ float bf2f(unsigned short s) {
    return __uint_as_float(((unsigned)s) << 16);
}

// ---------------------------------------------------------------- cast f32 -> bf16
__global__ __launch_bounds__(256)
void k_cast(const float* __restrict__ in, unsigned short* __restrict__ out) {
    const size_t i = ((size_t)blockIdx.x * 256 + threadIdx.x) * 4;
    float4 v = *(const float4*)(in + i);
    ushort4 o;
    o.x = f2bf(v.x); o.y = f2bf(v.y); o.z = f2bf(v.z); o.w = f2bf(v.w);
    *(ushort4*)(out + i) = o;
}

// ---------------------------------------------------------------- fused 4x transpose+cast
__global__ __launch_bounds__(256)
void k_wtrans4(const float* __restrict__ w0, const float* __restrict__ w1,
               const float* __restrict__ w2, const float* __restrict__ w3,
               unsigned short* __restrict__ d0, unsigned short* __restrict__ d1,
               unsigned short* __restrict__ d2, unsigned short* __restrict__ d3) {
    const int z = blockIdx.z;
    const float* in = (z == 0) ? w0 : (z == 1) ? w1 : (z == 2) ? w2 : w3;
    unsigned short* out = (z == 0) ? d0 : (z == 1) ? d1 : (z == 2) ? d2 : d3;
    __shared__ unsigned short tile[32][33];
    const int t  = threadIdx.x;
    const int r  = t >> 3;
    const int c4 = (t & 7) << 2;
    const size_t ib = ((size_t)blockIdx.y * 32 + r) * 2048 + blockIdx.x * 32 + c4;
    float4 v = *(const float4*)(in + ib);
    tile[r][c4 + 0] = f2bf(v.x); tile[r][c4 + 1] = f2bf(v.y);
    tile[r][c4 + 2] = f2bf(v.z); tile[r][c4 + 3] = f2bf(v.w);
    __syncthreads();
    ushort4 o;
    o.x = tile[c4 + 0][r]; o.y = tile[c4 + 1][r];
    o.z = tile[c4 + 2][r]; o.w = tile[c4 + 3][r];
    const size_t ob = ((size_t)blockIdx.x * 32 + r) * 2048 + blockIdx.y * 32 + c4;
    *(ushort4*)(out + ob) = o;
}

// ---------------------------------------------------------------- shared pipeline macros
#define FENCE asm volatile("" ::: "memory")
#define BAR   do { FENCE; __builtin_amdgcn_s_barrier(); FENCE; } while (0)
#define WVM4  asm volatile("s_waitcnt vmcnt(4)" ::: "memory")
#define WVM3  asm volatile("s_waitcnt vmcnt(3)" ::: "memory")
#define WVM2  asm volatile("s_waitcnt vmcnt(2)" ::: "memory")
#define WVM0  asm volatile("s_waitcnt vmcnt(0)" ::: "memory")

// ---------------------------------------------------------------- fused QKV GEMM
// 256x192 tile, BK=64, 512 blocks = 2 perfect rounds. (UNCHANGED from round 5
// — control kernel this round.) 8 waves 4Mx2N, A dbuf + B triple-buf, single
// barrier + counted vmcnt(3) per K-tile, T2 chunk swizzle, XCD 8x8 regions.
#define AB0 0
#define AB1 16384
#define BB0 32768

#define QSTG_A(abufe, u, kt)                                                    \
    gld_lds16(aS + ((size_t)(u) * 64) * D_ + (kt) * 64,                         \
              &lds[(abufe) + (u) * 4096 + t * 8])
#define QSTG_B(bbufe, u, kt)                                                    \
    gld_lds16(bS + ((size_t)(u) * 64) * D_ + (kt) * 64,                         \
              &lds[(bbufe) + (u) * 4096 + t * 8])
#define QDSA2(abufe) do {                                                       \
    _Pragma("unroll") for (int mi = 0; mi < 2; mi++)                            \
    _Pragma("unroll") for (int kk = 0; kk < 2; kk++)                            \
    _Pragma("unroll") for (int i = 0; i < 2; i++)                               \
        af[mi][kk][i] = *(const bf16x8_t*)&lds[(abufe) +                        \
            (wm + mi * 32 + i * 16 + l16) * 64 + (kk ? sw1 : sw0)];             \
} while (0)
#define QDSB(bbufe) do {                                                        \
    _Pragma("unroll") for (int kk = 0; kk < 2; kk++)                            \
    _Pragma("unroll") for (int jj = 0; jj < 6; jj++)                            \
        bfr[kk][jj] = *(const bf16x8_t*)&lds[(bbufe) +                          \
            (wn + jj * 16 + l16) * 64 + (kk ? sw1 : sw0)];                      \
} while (0)
#define MMALL2 do {                                                             \
    __builtin_amdgcn_s_setprio(1);                                              \
    _Pragma("unroll") for (int mi = 0; mi < 2; mi++)                            \
    _Pragma("unroll") for (int kk = 0; kk < 2; kk++)                            \
    _Pragma("unroll") for (int i = 0; i < 2; i++)                               \
    _Pragma("unroll") for (int jj = 0; jj < 6; jj++)                            \
        acc[mi * 2 + i][jj] = __builtin_amdgcn_mfma_f32_16x16x32_bf16(          \
            af[mi][kk][i], bfr[kk][jj], acc[mi * 2 + i][jj], 0, 0, 0);          \
    __builtin_amdgcn_s_setprio(0);                                              \
} while (0)

__global__ __launch_bounds__(512, 2)
void k_gemm_qkv(const __hip_bfloat16* __restrict__ A,
                const __hip_bfloat16* __restrict__ Bt,
                const float* __restrict__ bq, const float* __restrict__ bk,
                const float* __restrict__ bv,
                __hip_bfloat16* __restrict__ qo, __hip_bfloat16* __restrict__ ko,
                __hip_bfloat16* __restrict__ vTo) {
    __shared__ __align__(16) __hip_bfloat16 lds[69632];  // 136 KiB

    const int wg   = blockIdx.x;
    const int xcd  = wg & 7;
    const int loc  = wg >> 3;                  // 0..63
    const int bx   = ((xcd & 1) << 3) + (loc & 7);    // 16 M-tiles
    const int by   = ((xcd >> 1) << 3) + (loc >> 3);  // 32 N-tiles
    const int tileM = bx << 8;                 // BM=256
    const int tileN = by * 192;                // BN=192

    const int t    = threadIdx.x;
    const int lane = t & 63;
    const int wave = t >> 6;
    const int quad = lane >> 4;
    const int l16  = lane & 15;
    const int wm   = (wave >> 1) << 6;         // 0/64/128/192
    const int wn   = (wave & 1) * 96;          // 0/96

    const int sw0 = ((quad)     ^ (l16 & 7)) << 3;
    const int sw1 = ((quad + 4) ^ (l16 & 7)) << 3;

    const int r8  = t >> 3;                    // 0..63
    const int qch = (t & 7) ^ (r8 & 7);
    const __hip_bfloat16* aS = A  + (size_t)(tileM + r8) * D_ + qch * 8;
    const __hip_bfloat16* bS = Bt + (size_t)(tileN + r8) * D_ + qch * 8;

    QSTG_A(AB0, 0, 0); QSTG_A(AB0, 1, 0); QSTG_A(AB0, 2, 0); QSTG_A(AB0, 3, 0);
    QSTG_B(BB0, 0, 0); QSTG_B(BB0, 1, 0); QSTG_B(BB0, 2, 0);
    QSTG_B(BB0 + 12288, 0, 1); QSTG_B(BB0 + 12288, 1, 1); QSTG_B(BB0 + 12288, 2, 1);
    WVM3;
    BAR;

    f32x4_t acc[4][6];
#pragma unroll
    for (int i = 0; i < 4; i++)
#pragma unroll
        for (int j = 0; j < 6; j++) acc[i][j] = (f32x4_t){0.f, 0.f, 0.f, 0.f};
    bf16x8_t af[2][2][2], bfr[2][6];

    int rbm = 0;
    int sbm = 2;
#pragma unroll 1
    for (int it = 0; it < 32; ++it) {
        const int ra = (it & 1) ? AB1 : AB0;
        const int sa = (it & 1) ? AB0 : AB1;
        const int rb = BB0 + rbm * 12288;
        const int sb = BB0 + sbm * 12288;
        const bool stA = (it + 1 < 32);
        const bool stB = (it + 2 < 32);

        if (stA) { QSTG_A(sa, 0, it + 1); QSTG_A(sa, 1, it + 1);
                   QSTG_A(sa, 2, it + 1); QSTG_A(sa, 3, it + 1); }
        if (stB) { QSTG_B(sb, 0, it + 2); QSTG_B(sb, 1, it + 2);
                   QSTG_B(sb, 2, it + 2); }

        QDSA2(ra);
        QDSB(rb);
        MMALL2;

        if (stB) { WVM3; } else if (stA) { WVM0; }
        BAR;

        rbm = (rbm == 2) ? 0 : rbm + 1;
        sbm = (sbm == 2) ? 0 : sbm + 1;
    }

#pragma unroll
    for (int ai = 0; ai < 4; ai++) {
        const int m = tileM + wm + ai * 16 + quad * 4;
#pragma unroll
        for (int bj = 0; bj < 6; bj++) {
            const int n0  = tileN + wn + bj * 16;
            const int sel = n0 >> 11;            // 0=q, 1=k, 2=v
            const int n   = (n0 & (INNER_ - 1)) + l16;
            if (sel < 2) {
                const float* bias = sel ? bk : bq;
                __hip_bfloat16* C = sel ? ko : qo;
                const float bn = bias[n];
#pragma unroll
                for (int r = 0; r < 4; r++)
                    C[(size_t)(m + r) * INNER_ + n] =
                        __float2bfloat16(acc[ai][bj][r] + bn);
            } else {
                const int hh = n >> 7, dd = n & 127;
                const int bb = tileM >> 11;
                const int l0 = m & (L_ - 1);
                const float bvn = bv[n];
                ushort4 pk;
                pk.x = f2bf(acc[ai][bj][0] + bvn);
                pk.y = f2bf(acc[ai][bj][1] + bvn);
                pk.z = f2bf(acc[ai][bj][2] + bvn);
                pk.w = f2bf(acc[ai][bj][3] + bvn);
                *(ushort4*)(vTo + ((size_t)(bb * H_ + hh) * DH_ + dd) * L_ + l0) = pk;
            }
        }
    }
}

// ---------------------------------------------------------------- wo GEMM (new)
// Same pipeline as k_gemm_qkv at 256x128: grid 16x16 = 256 blocks = 1 perfect
// round, 512 threads, 8 waves 4Mx2N (wave 64x64, acc[4][4]). LDS: A[256][64]
// dbuf (2x32KB) + B[128][64] triple (3x16KB) = 112 KiB. Units: A=4, B=2 per
// K-tile. Ledger: stage A(t+1)x4 + B(t+2)x2; wait WVM2 retires A(t+1)+B(t+1),
// leaves B(t+2)x2. Prologue A(0)x4,B(0)x2,B(1)x2 -> WVM2. Tail it=30 WVM0.
#define WAB0 0
#define WAB1 16384
#define WBB0 32768

#define WSTG_A(abufe, u, kt)                                                    \
    gld_lds16(aS + ((size_t)(u) * 64) * INNER_ + (kt) * 64,                     \
              &lds[(abufe) + (u) * 4096 + t * 8])
#define WSTG_B(bbufe, u, kt)                                                    \
    gld_lds16(bS + ((size_t)(u) * 64) * INNER_ + (kt) * 64,                     \
              &lds[(bbufe) + (u) * 4096 + t * 8])
#define WDSA(abufe) do {                                                        \
    _Pragma("unroll") for (int kk = 0; kk < 2; kk++)                            \
    _Pragma("unroll") for (int i = 0; i < 4; i++)                               \
        af[kk][i] = *(const bf16x8_t*)&lds[(abufe) +                            \
            (wm + i * 16 + l16) * 64 + (kk ? sw1 : sw0)];                       \
} while (0)
#define WDSB(bbufe) do {                                                        \
    _Pragma("unroll") for (int kk = 0; kk < 2; kk++)                            \
    _Pragma("unroll") for (int jj = 0; jj < 4; jj++)                            \
        bfr[kk][jj] = *(const bf16x8_t*)&lds[(bbufe) +                          \
            (wn + jj * 16 + l16) * 64 + (kk ? sw1 : sw0)];                      \
} while (0)
#define WMM do {                                                                \
    __builtin_amdgcn_s_setprio(1);                                              \
    _Pragma("unroll") for (int kk = 0; kk < 2; kk++)                            \
    _Pragma("unroll") for (int i = 0; i < 4; i++)                               \
    _Pragma("unroll") for (int jj = 0; jj < 4; jj++)                            \
        acc[i][jj] = __builtin_amdgcn_mfma_f32_16x16x32_bf16(                   \
            af[kk][i], bfr[kk][jj], acc[i][jj], 0, 0, 0);                       \
    __builtin_amdgcn_s_setprio(0);                                              \
} while (0)

__global__ __launch_bounds__(512, 2)
void k_gemm_wo(const __hip_bfloat16* __restrict__ A,
               const __hip_bfloat16* __restrict__ Bt,
               const float* __restrict__ bias,
               float* __restrict__ C) {
    __shared__ __align__(16) __hip_bfloat16 lds[57344];  // 112 KiB

    // bijective XCD swizzle: 256 blocks, each XCD an 8bx x 4by region
    const int wg   = blockIdx.x;
    const int xcd  = wg & 7;
    const int loc  = wg >> 3;                  // 0..31
    const int bx   = ((xcd & 1) << 3) + (loc & 7);    // 16 M-tiles
    const int by   = ((xcd >> 1) << 2) + (loc >> 3);  // 16 N-tiles
    const int tileM = bx << 8;                 // BM=256
    const int tileN = by << 7;                 // BN=128

    const int t    = threadIdx.x;
    const int lane = t & 63;
    const int wave = t >> 6;
    const int quad = lane >> 4;
    const int l16  = lane & 15;
    const int wm   = (wave >> 1) << 6;         // 0/64/128/192
    const int wn   = (wave & 1) << 6;          // 0/64

    const int sw0 = ((quad)     ^ (l16 & 7)) << 3;
    const int sw1 = ((quad + 4) ^ (l16 & 7)) << 3;

    const int r8  = t >> 3;                    // 0..63
    const int qch = (t & 7) ^ (r8 & 7);
    const __hip_bfloat16* aS = A  + (size_t)(tileM + r8) * INNER_ + qch * 8;
    const __hip_bfloat16* bS = Bt + (size_t)(tileN + r8) * INNER_ + qch * 8;

    // prologue: A(0)x4, B(0)x2, B(1)x2; retire A0,B0, leave B1x2 in flight
    WSTG_A(WAB0, 0, 0); WSTG_A(WAB0, 1, 0); WSTG_A(WAB0, 2, 0); WSTG_A(WAB0, 3, 0);
    WSTG_B(WBB0, 0, 0); WSTG_B(WBB0, 1, 0);
    WSTG_B(WBB0 + 8192, 0, 1); WSTG_B(WBB0 + 8192, 1, 1);
    WVM2;
    BAR;

    f32x4_t acc[4][4];
#pragma unroll
    for (int i = 0; i < 4; i++)
#pragma unroll
        for (int j = 0; j < 4; j++) acc[i][j] = (f32x4_t){0.f, 0.f, 0.f, 0.f};
    bf16x8_t af[2][4], bfr[2][4];

    int rbm = 0;
    int sbm = 2;
#pragma unroll 1
    for (int it = 0; it < 32; ++it) {
        const int ra = (it & 1) ? WAB1 : WAB0;
        const int sa = (it & 1) ? WAB0 : WAB1;
        const int rb = WBB0 + rbm * 8192;
        const int sb = WBB0 + sbm * 8192;
        const bool stA = (it + 1 < 32);
        const bool stB = (it + 2 < 32);

        if (stA) { WSTG_A(sa, 0, it + 1); WSTG_A(sa, 1, it + 1);
                   WSTG_A(sa, 2, it + 1); WSTG_A(sa, 3, it + 1); }
        if (stB) { WSTG_B(sb, 0, it + 2); WSTG_B(sb, 1, it + 2); }

        WDSA(ra);
        WDSB(rb);
        WMM;

        if (stB) { WVM2; } else if (stA) { WVM0; }
        BAR;

        rbm = (rbm == 2) ? 0 : rbm + 1;
        sbm = (sbm == 2) ? 0 : sbm + 1;
    }

#pragma unroll
    for (int i = 0; i < 4; i++) {
        const int m = tileM + wm + i * 16 + quad * 4;
#pragma unroll
        for (int j = 0; j < 4; j++) {
            const int n = tileN + wn + j * 16 + l16;
            const float bn = bias[n];
#pragma unroll
            for (int r = 0; r < 4; r++)
                C[(size_t)(m + r) * D_ + n] = acc[i][j][r] + bn;
        }
    }
}

// ---------------------------------------------------------------- RMSNorm + RoPE (q&k fused)
__global__ __launch_bounds__(256)
void k_rmsrope2(__hip_bfloat16* __restrict__ qb, __hip_bfloat16* __restrict__ kb,
                const float* __restrict__ qn, const float* __restrict__ kn,
                const float* __restrict__ pcos, const float* __restrict__ psin,
                const float* __restrict__ lls, float qextra) {
    const int which = blockIdx.y;
    __hip_bfloat16* buf = which ? kb : qb;
    const float* w = which ? kn : qn;
    const int row = blockIdx.x;
    const int l   = row & (L_ - 1);
    const int t   = threadIdx.x;
    __hip_bfloat16* p = buf + (size_t)row * INNER_ + t * 8;

    float x[8];
    {
        const unsigned short* ps = (const unsigned short*)p;
        ushort4 a = *(const ushort4*)ps;
        ushort4 b = *(const ushort4*)(ps + 4);
        unsigned short s[8] = {a.x, a.y, a.z, a.w, b.x, b.y, b.z, b.w};
#pragma unroll
        for (int i = 0; i < 8; i++) x[i] = bf2f(s[i]);
    }
    float ss = 0.f;
#pragma unroll
    for (int i = 0; i < 8; i++) ss += x[i] * x[i];
#pragma unroll
    for (int off = 32; off >= 1; off >>= 1) ss += __shfl_down(ss, off);
    __shared__ float red[4];
    if ((t & 63) == 0) red[t >> 6] = ss;
    __syncthreads();
    ss = red[0] + red[1] + red[2] + red[3];
    const float rstd = rsqrtf(ss * (1.0f / (float)INNER_) + 1e-6f);

    const float scale = which ? 1.0f : (qextra * lls[l]);

    const float4 c4 = ((const float4*)(pcos + (size_t)l * (INNER_ / 2)))[t];
    const float4 s4 = ((const float4*)(psin + (size_t)l * (INNER_ / 2)))[t];
    const float cc[4] = {c4.x, c4.y, c4.z, c4.w};
    const float sn[4] = {s4.x, s4.y, s4.z, s4.w};
    const float4 w0 = ((const float4*)w)[t * 2];
    const float4 w1 = ((const float4*)w)[t * 2 + 1];
    const float ww[8] = {w0.x, w0.y, w0.z, w0.w, w1.x, w1.y, w1.z, w1.w};

    union { __hip_bfloat16 h[8]; uint4 u; } pk;
#pragma unroll
    for (int pi = 0; pi < 4; pi++) {
        const float y1 = x[pi * 2]     * rstd * ww[pi * 2];
        const float y2 = x[pi * 2 + 1] * rstd * ww[pi * 2 + 1];
        pk.h[pi * 2]     = __float2bfloat16((y1 * cc[pi] - y2 * sn[pi]) * scale);
        pk.h[pi * 2 + 1] = __float2bfloat16((y1 * sn[pi] + y2 * cc[pi]) * scale);
    }
    *(uint4*)p = pk.u;
}

// ---------------------------------------------------------------- attention
// Round-6 change: double-buffered K/V staging with raw barriers + counted
// vmcnt(4) (T14/T3). Per key-tile: stage kt+1 into buf^1, WVM4 (retires kt's 4
// loads, leaves kt+1's 4 in flight), BAR, compute(cur), BAR. No more full
// vmcnt(0) drain per tile. Barriers are block-uniform (causal skip guards
// compute only). Epilogue stores retire at the next counted wait harmlessly.
__global__ __launch_bounds__(512)
void k_attn(const __hip_bfloat16* __restrict__ q,
            const __hip_bfloat16* __restrict__ k,
            const __hip_bfloat16* __restrict__ vT,
            __hip_bfloat16* __restrict__ o) {
    __shared__ __align__(16) __hip_bfloat16 Ks[2][64 * 128];   // [key][d] swizzled
    __shared__ __align__(16) __hip_bfloat16 Vs[2][128 * 64];   // [d][key] swizzled
    __shared__ __align__(16) __hip_bfloat16 Pt[8][16 * 72];    // [wave][qrow][key]

    const int p  = blockIdx.x;   // 0..7
    const int bh = blockIdx.y;
    const int b  = bh >> 4;
    const int h  = bh & 15;
    const int t = threadIdx.x, wave = t >> 6, lane = t & 63;
    const int quad = lane >> 4, l16 = lane & 15;

    const int kr = t >> 4;                          // 0..31
    const int kc = ((t & 15) ^ (kr & 15)) << 3;
    const int vr = t >> 3;                          // 0..63
    const int vc = ((t & 7) ^ (vr & 7)) << 3;
    const __hip_bfloat16* kbase = k  + (size_t)b * L_ * INNER_ + h * DH_;
    const __hip_bfloat16* vbase = vT + (size_t)bh * DH_ * L_;

#define STGKV(kt_, b_) do {                                                      \
    const int kv0_ = (kt_) * 64;                                                 \
    gld_lds16(kbase + (size_t)(kv0_ + kr)      * INNER_ + kc, &Ks[b_][t * 8]);   \
    gld_lds16(kbase + (size_t)(kv0_ + 32 + kr) * INNER_ + kc, &Ks[b_][4096 + t * 8]); \
    gld_lds16(vbase + (size_t)vr        * L_ + kv0_ + vc, &Vs[b_][t * 8]);       \
    gld_lds16(vbase + (size_t)(64 + vr) * L_ + kv0_ + vc, &Vs[b_][4096 + t * 8]);\
} while (0)

    for (int half = 0; half < 2; ++half) {
        const int qt = half ? (15 - p) : p;
        const int rowbase = qt * 128 + wave * 16;

        bf16x8_t aq[4];
        {
            const size_t qoff = (size_t)(b * L_ + rowbase + l16) * INNER_ + h * DH_;
#pragma unroll
            for (int kk = 0; kk < 4; kk++)
                aq[kk] = *(const bf16x8_t*)(q + qoff + kk * 32 + quad * 8);
        }

        f32x4_t oacc[8];
#pragma unroll
        for (int jj = 0; jj < 8; jj++) oacc[jj] = (f32x4_t){0.f, 0.f, 0.f, 0.f};
        float m_ = -1e30f, l_ = 0.f;

        const int nkt = 2 * qt + 2;
        STGKV(0, 0);                              // prologue
#pragma unroll 1
        for (int kt = 0; kt < nkt; ++kt) {
            const int kv0 = kt * 64;
            const int cur = kt & 1;
            const bool more = (kt + 1 < nkt);
            if (more) STGKV(kt + 1, cur ^ 1);     // prefetch next tile
            if (more) { WVM4; } else { WVM0; }    // current tile's 4 loads done
            BAR;

            if (kv0 <= rowbase + 15) {
                // S^T = K . Q^T
                f32x4_t sacc[4];
#pragma unroll
                for (int tt = 0; tt < 4; tt++) sacc[tt] = (f32x4_t){0.f, 0.f, 0.f, 0.f};
#pragma unroll
                for (int kk = 0; kk < 4; kk++) {
                    bf16x8_t kf[4];
#pragma unroll
                    for (int tt = 0; tt < 4; tt++)
                        kf[tt] = *(const bf16x8_t*)&Ks[cur][(tt * 16 + l16) * 128 + (((kk * 4 + quad) ^ l16) << 3)];
#pragma unroll
                    for (int tt = 0; tt < 4; tt++)
                        sacc[tt] = __builtin_amdgcn_mfma_f32_16x16x32_bf16(
                            kf[tt], aq[kk], sacc[tt], 0, 0, 0);
                }

                if (kv0 + 63 > rowbase) {         // diagonal tile: causal mask
                    const int qrow = rowbase + l16;
#pragma unroll
                    for (int tt = 0; tt < 4; tt++)
#pragma unroll
                        for (int r = 0; r < 4; r++)
                            if (kv0 + tt * 16 + quad * 4 + r > qrow) sacc[tt][r] = -1e30f;
                }

                float mx = sacc[0][0];
#pragma unroll
                for (int tt = 0; tt < 4; tt++)
#pragma unroll
                    for (int r = 0; r < 4; r++) mx = fmaxf(mx, sacc[tt][r]);
                mx = fmaxf(mx, __shfl_xor(mx, 16));
                mx = fmaxf(mx, __shfl_xor(mx, 32));
                const float mnew = fmaxf(m_, mx);
                const float alpha = exp2f(m_ - mnew);
                m_ = mnew;

                float ls = 0.f;
#pragma unroll
                for (int tt = 0; tt < 4; tt++) {
                    ushort4 pk;
                    float p0 = exp2f(sacc[tt][0] - mnew);
                    float p1 = exp2f(sacc[tt][1] - mnew);
                    float p2 = exp2f(sacc[tt][2] - mnew);
                    float p3 = exp2f(sacc[tt][3] - mnew);
                    ls += (p0 + p1) + (p2 + p3);
                    pk.x = f2bf(p0); pk.y = f2bf(p1); pk.z = f2bf(p2); pk.w = f2bf(p3);
                    *(ushort4*)&Pt[wave][l16 * 72 + tt * 16 + quad * 4] = pk;
                }
                ls += __shfl_xor(ls, 16);
                ls += __shfl_xor(ls, 32);
                l_ = l_ * alpha + ls;
#pragma unroll
                for (int jj = 0; jj < 8; jj++) {
                    oacc[jj][0] *= alpha; oacc[jj][1] *= alpha;
                    oacc[jj][2] *= alpha; oacc[jj][3] *= alpha;
                }

                // O^T += V^T . P^T
#pragma unroll
                for (int kk2 = 0; kk2 < 2; kk2++) {
                    bf16x8_t pf = *(const bf16x8_t*)&Pt[wave][l16 * 72 + kk2 * 32 + quad * 8];
#pragma unroll
                    for (int jj = 0; jj < 8; jj++) {
                        bf16x8_t vf = *(const bf16x8_t*)
                            &Vs[cur][(jj * 16 + l16) * 64 + (((kk2 * 4 + quad) ^ (l16 & 7)) << 3)];
                        oacc[jj] = __builtin_amdgcn_mfma_f32_16x16x32_bf16(vf, pf, oacc[jj], 0, 0, 0);
                    }
                }
            }
            BAR;                                   // all reads of cur done before overwrite
        }

        {
            const float inv = 1.0f / l_;
            __hip_bfloat16* orow = o + (size_t)(b * L_ + rowbase + l16) * INNER_ + h * DH_;
#pragma unroll
            for (int jj = 0; jj < 8; jj++) {
                ushort4 pk;
                pk.x = f2bf(oacc[jj][0] * inv);
                pk.y = f2bf(oacc[jj][1] * inv);
                pk.z = f2bf(oacc[jj][2] * inv);
                pk.w = f2bf(oacc[jj][3] * inv);
                *(ushort4*)(orow + jj * 16 + quad * 4) = pk;
            }
        }
    }
#undef STGKV
}

// ---------------------------------------------------------------- launch
extern "C" void kernel_launch(void* const* d_in, const int* in_sizes, int n_in,
                              void* d_out, int out_size, void* d_ws, size_t ws_size,
                              hipStream_t stream) {
    const float* x      = (const float*)d_in[0];
    const float* pe_cos = (const float*)d_in[1];
    const float* pe_sin = (const float*)d_in[2];
    const float* lls    = (const float*)d_in[3];
    const float* wq     = (const float*)d_in[4];
    const float* bq     = (const float*)d_in[5];
    const float* wk     = (const float*)d_in[6];
    const float* bk     = (const float*)d_in[7];
    const float* wv     = (const float*)d_in[8];
    const float* bv     = (const float*)d_in[9];
    const float* qn     = (const float*)d_in[10];
    const float* kn     = (const float*)d_in[11];
    const float* wo     = (const float*)d_in[12];
    const float* bo     = (const float*)d_in[13];

    char* ws = (char*)d_ws;
    const size_t SZ_W = (size_t)D_ * INNER_ * 2;   // 8 MB (bf16)
    const size_t SZ_M = (size_t)M_ * INNER_ * 2;   // 16 MB (bf16)
    __hip_bfloat16* xb     = (__hip_bfloat16*)ws;  ws += SZ_M;
    __hip_bfloat16* wqkvT  = (__hip_bfloat16*)ws;  ws += 3 * SZ_W;  // [6144][2048]
    __hip_bfloat16* woT    = (__hip_bfloat16*)ws;  ws += SZ_W;
    __hip_bfloat16* qb     = (__hip_bfloat16*)ws;  ws += SZ_M;
    __hip_bfloat16* kb     = (__hip_bfloat16*)ws;  ws += SZ_M;
    __hip_bfloat16* vT     = (__hip_bfloat16*)ws;  ws += SZ_M;
    __hip_bfloat16* ab     = (__hip_bfloat16*)ws;  ws += SZ_M;
    (void)in_sizes; (void)n_in; (void)out_size; (void)ws_size;

    const dim3 tb(256);

    // 0. cast x to bf16
    k_cast<<<(M_ * D_) / 1024, tb, 0, stream>>>(x, (unsigned short*)xb);

    // 1. all 4 weight transpose+casts in one dispatch
    k_wtrans4<<<dim3(64, 64, 4), tb, 0, stream>>>(
        wq, wk, wv, wo,
        (unsigned short*)wqkvT,
        (unsigned short*)(wqkvT + (size_t)INNER_ * D_),
        (unsigned short*)(wqkvT + 2 * (size_t)INNER_ * D_),
        (unsigned short*)woT);

    // 2. fused QKV projection (unchanged control)
    k_gemm_qkv<<<dim3(512), dim3(512), 0, stream>>>(xb, wqkvT, bq, bk, bv, qb, kb, vT);

    // 3. RMSNorm + RoPE for q and k in one dispatch
    const float qextra = 0.08838834764831843f /* rsqrt(128) */ * 1.4426950408889634f /* log2 e */;
    k_rmsrope2<<<dim3(M_, 2), tb, 0, stream>>>(qb, kb, qn, kn, pe_cos, pe_sin, lls, qextra);

    // 4. causal flash attention, double-buffered K/V staging
    k_attn<<<dim3(8, B_ * H_), dim3(512), 0, stream>>>(qb, kb, vT, ab);

    // 5. output projection -> d_out (f32), 256x128 pipelined structure
    k_gemm_wo<<<dim3(256), dim3(512), 0, stream>>>(ab, woT, bo, (float*)d_out);
}